// Round 2
// baseline (13498.064 us; speedup 1.0000x reference)
//
#include <hip/hip_runtime.h>
#include <hip/hip_bf16.h>

// Problem constants
constexpr int BATCH = 8;
constexpr int SEQ   = 1024;
constexpr int CH    = 1536;
constexpr int NH    = 12;
constexpr int HD    = 128;       // head dim
constexpr int FFDIM = 6144;      // 4*CH
constexpr int NROWS = BATCH * SEQ;   // 8192
constexpr int FFCHUNK = 2048;    // rows per FF chunk (FFCHUNK*FFDIM == NROWS*CH)
constexpr float EPS = 1e-5f;

// ---------------- block reduction helpers (blockDim == 256) ----------------
__device__ __forceinline__ float block_sum(float v, float* red) {
#pragma unroll
  for (int o = 32; o > 0; o >>= 1) v += __shfl_down(v, o, 64);
  const int w = threadIdx.x >> 6;
  if ((threadIdx.x & 63) == 0) red[w] = v;
  __syncthreads();
  const float r = red[0] + red[1] + red[2] + red[3];
  __syncthreads();
  return r;
}

__device__ __forceinline__ float block_max(float v, float* red) {
#pragma unroll
  for (int o = 32; o > 0; o >>= 1) v = fmaxf(v, __shfl_down(v, o, 64));
  const int w = threadIdx.x >> 6;
  if ((threadIdx.x & 63) == 0) red[w] = v;
  __syncthreads();
  const float r = fmaxf(fmaxf(red[0], red[1]), fmaxf(red[2], red[3]));
  __syncthreads();
  return r;
}

// ---------------- LayerNorm over last dim (CH) ----------------
__global__ __launch_bounds__(256) void ln_kernel(const float* __restrict__ x,
                                                 const float* __restrict__ g,
                                                 const float* __restrict__ b,
                                                 float* __restrict__ out) {
  __shared__ float row[CH];
  __shared__ float red[4];
  const size_t base = (size_t)blockIdx.x * CH;
  float s = 0.f;
  for (int c = threadIdx.x; c < CH; c += 256) {
    const float v = x[base + c];
    row[c] = v;
    s += v;
  }
  const float mean = block_sum(s, red) * (1.0f / CH);
  float s2 = 0.f;
  for (int c = threadIdx.x; c < CH; c += 256) {
    const float d = row[c] - mean;
    s2 += d * d;
  }
  const float var = block_sum(s2, red) * (1.0f / CH);
  const float rstd = rsqrtf(var + EPS);
  for (int c = threadIdx.x; c < CH; c += 256)
    out[base + c] = (row[c] - mean) * rstd * g[c] + b[c];
}

// ---------------- generic tiled fp32 GEMM ----------------
// C[m,n] (+ bias[n]) (relu) (+ res[m,n]) = sum_k A[m,k]*B[k,n]
// grid.z batches B (stride bstride elems) and C (offset cstride elems).
// All dims are multiples of the tile sizes here; no bounds checks.
// NOTE: res may alias Cm (same rows): each element is read then written by
// the same thread, so in-place residual-add is safe.
constexpr int GT = 64;   // output tile (M and N)
constexpr int GK = 16;   // K tile
constexpr int GPAD = 68; // padded leading dim for LDS tiles

template <int RELU, int BIAS, int RES>
__global__ __launch_bounds__(256) void gemm_kernel(
    const float* __restrict__ A, int lda,
    const float* __restrict__ Bm, int ldb, long bstride,
    float* __restrict__ Cm, int ldc, long cstride,
    const float* __restrict__ bias,
    const float* __restrict__ res, int ldr,
    int K) {
  __shared__ __align__(16) float As[GK][GPAD];  // [k][m]
  __shared__ __align__(16) float Bs[GK][GPAD];  // [k][n]
  const int z = blockIdx.z;
  const float* Bp = Bm + (size_t)z * bstride;
  float* Cp = Cm + (size_t)z * cstride;
  const int m0 = blockIdx.y * GT;
  const int n0 = blockIdx.x * GT;
  const int tid = threadIdx.x;
  const int tx = tid & 15, ty = tid >> 4;
  const int arow = tid >> 2, akq = (tid & 3) * 4;   // A: 64 rows x 16 k, float4 per thread
  const int brow = tid >> 4, bcol = (tid & 15) * 4; // B: 16 k x 64 n, float4 per thread
  const float* Aptr = A + (size_t)(m0 + arow) * lda + akq;
  const float* Bptr = Bp + (size_t)brow * ldb + n0 + bcol;

  float acc[4][4] = {};
  for (int k0 = 0; k0 < K; k0 += GK) {
    const float4 av = *(const float4*)(Aptr + k0);
    const float4 bv = *(const float4*)(Bptr + (size_t)k0 * ldb);
    __syncthreads();
    As[akq + 0][arow] = av.x;
    As[akq + 1][arow] = av.y;
    As[akq + 2][arow] = av.z;
    As[akq + 3][arow] = av.w;
    *(float4*)&Bs[brow][bcol] = bv;
    __syncthreads();
#pragma unroll
    for (int kk = 0; kk < GK; ++kk) {
      const float4 a = *(const float4*)&As[kk][ty * 4];
      const float4 b = *(const float4*)&Bs[kk][tx * 4];
      acc[0][0] += a.x * b.x; acc[0][1] += a.x * b.y; acc[0][2] += a.x * b.z; acc[0][3] += a.x * b.w;
      acc[1][0] += a.y * b.x; acc[1][1] += a.y * b.y; acc[1][2] += a.y * b.z; acc[1][3] += a.y * b.w;
      acc[2][0] += a.z * b.x; acc[2][1] += a.z * b.y; acc[2][2] += a.z * b.z; acc[2][3] += a.z * b.w;
      acc[3][0] += a.w * b.x; acc[3][1] += a.w * b.y; acc[3][2] += a.w * b.z; acc[3][3] += a.w * b.w;
    }
  }
#pragma unroll
  for (int i = 0; i < 4; ++i) {
    const size_t m = (size_t)(m0 + ty * 4 + i);
#pragma unroll
    for (int j = 0; j < 4; ++j) {
      const int n = n0 + tx * 4 + j;
      float v = acc[i][j];
      if (BIAS) v += bias[n];
      if (RELU) v = fmaxf(v, 0.f);
      if (RES) v += res[m * (size_t)ldr + n];
      Cp[m * (size_t)ldc + n] = v;
    }
  }
}

// ---------------- causal attention, one block per (t, b*h) ----------------
// q,k,v,o layout: (B, T, H, D) i.e. elem (b,t,h,d) at ((b*SEQ+t)*CH + h*HD + d)
__global__ __launch_bounds__(256) void attn_kernel(const float* __restrict__ q,
                                                   const float* __restrict__ k,
                                                   const float* __restrict__ v,
                                                   float* __restrict__ o) {
  __shared__ __align__(16) float qs[HD];
  __shared__ float sc[SEQ];
  __shared__ float red[4];
  __shared__ float partial[HD];
  const int t = blockIdx.x;
  const int b = blockIdx.y / NH;
  const int h = blockIdx.y % NH;
  const size_t base = (size_t)b * SEQ * CH + (size_t)h * HD;
  const int n = t + 1;  // causal: s in [0, t]
  if (threadIdx.x < HD) qs[threadIdx.x] = q[base + (size_t)t * CH + threadIdx.x];
  __syncthreads();
  const float scale = 0.08838834764831845f;  // 1/sqrt(128)
  float lmax = -3.0e38f;
  for (int s = threadIdx.x; s < n; s += 256) {
    const float4* kr = (const float4*)(k + base + (size_t)s * CH);
    const float4* q4 = (const float4*)qs;
    float d0 = 0.f;
#pragma unroll
    for (int j = 0; j < HD / 4; ++j) {
      const float4 kv = kr[j];
      const float4 qv = q4[j];
      d0 += kv.x * qv.x + kv.y * qv.y + kv.z * qv.z + kv.w * qv.w;
    }
    d0 *= scale;
    sc[s] = d0;
    lmax = fmaxf(lmax, d0);
  }
  const float mx = block_max(lmax, red);
  float lsum = 0.f;
  for (int s = threadIdx.x; s < n; s += 256) {
    const float e = __expf(sc[s] - mx);
    sc[s] = e;
    lsum += e;
  }
  const float inv = 1.0f / block_sum(lsum, red);
  const int d0 = threadIdx.x & (HD - 1);
  const int half = threadIdx.x >> 7;  // 0 or 1
  float acc = 0.f;
  for (int s = half; s < n; s += 2)
    acc += sc[s] * v[base + (size_t)s * CH + d0];
  if (half) partial[d0] = acc;
  __syncthreads();
  if (!half) o[base + (size_t)t * CH + d0] = (acc + partial[d0]) * inv;
}

// ---------------- BatchNorm over (B, C) per T channel ----------------
__global__ __launch_bounds__(256) void bn_stats(const float* __restrict__ x,
                                                float* __restrict__ mean,
                                                float* __restrict__ rstd) {
  __shared__ float red[4];
  const int t = blockIdx.x;
  float s = 0.f;
  for (int bb = 0; bb < BATCH; ++bb) {
    const float* p = x + ((size_t)bb * SEQ + t) * CH;
    for (int c = threadIdx.x; c < CH; c += 256) s += p[c];
  }
  const float m = block_sum(s, red) * (1.0f / (BATCH * CH));
  float s2 = 0.f;
  for (int bb = 0; bb < BATCH; ++bb) {
    const float* p = x + ((size_t)bb * SEQ + t) * CH;
    for (int c = threadIdx.x; c < CH; c += 256) {
      const float d = p[c] - m;
      s2 += d * d;
    }
  }
  const float var = block_sum(s2, red) * (1.0f / (BATCH * CH));
  if (threadIdx.x == 0) {
    mean[t] = m;
    rstd[t] = rsqrtf(var + EPS);
  }
}

__global__ __launch_bounds__(256) void bn_apply(const float* __restrict__ x,
                                                float* __restrict__ out,
                                                const float* __restrict__ mean,
                                                const float* __restrict__ rstd,
                                                const float* __restrict__ g,
                                                const float* __restrict__ bb) {
  const size_t i = (size_t)blockIdx.x * 256 + threadIdx.x;
  const int t = (int)((i / CH) % SEQ);
  out[i] = (x[i] - mean[t]) * rstd[t] * g[t] + bb[t];
}

// ---------------- launch ----------------
extern "C" void kernel_launch(void* const* d_in, const int* in_sizes, int n_in,
                              void* d_out, int out_size, void* d_ws, size_t ws_size,
                              hipStream_t stream) {
  const float* x    = (const float*)d_in[0];
  const float* wq   = (const float*)d_in[1];
  const float* wk   = (const float*)d_in[2];
  const float* wv   = (const float*)d_in[3];
  const float* wo   = (const float*)d_in[4];
  const float* bo   = (const float*)d_in[5];
  const float* ln1g = (const float*)d_in[6];
  const float* ln1b = (const float*)d_in[7];
  const float* ln2g = (const float*)d_in[8];
  const float* ln2b = (const float*)d_in[9];
  const float* w1   = (const float*)d_in[10];
  const float* b1   = (const float*)d_in[11];
  const float* w2   = (const float*)d_in[12];
  const float* b2   = (const float*)d_in[13];
  const float* bn1g = (const float*)d_in[14];
  const float* bn1b = (const float*)d_in[15];
  const float* bn2g = (const float*)d_in[16];
  const float* bn2b = (const float*)d_in[17];
  float* out = (float*)d_out;   // also used as scratch (h_ln -> o -> h2 -> final)

  // Workspace layout (floats). Peak = 3*NC + 2*SEQ floats ~= 151 MB.
  //   ws0: Q -> X1 -> x2 (ff2 writes in place over X1)
  //   ws1: K -> ff1 chunk (FFCHUNK*FFDIM == NC floats exactly)
  //   ws2: V
  float* ws = (float*)d_ws;
  const size_t NC = (size_t)NROWS * CH;
  float* ws0 = ws;
  float* ws1 = ws + NC;
  float* ws2 = ws + 2 * NC;
  float* mean = ws + 3 * NC;
  float* rstd = ws + 3 * NC + SEQ;

  const dim3 blk(256);

  // 1. h_ln = LN1(x) -> out
  ln_kernel<<<NROWS, blk, 0, stream>>>(x, ln1g, ln1b, out);

  // 2. q/k/v = h_ln @ w{q,k,v}[h]  (batched over heads via grid.z)
  const dim3 gqkv(HD / GT, NROWS / GT, NH);
  gemm_kernel<0, 0, 0><<<gqkv, blk, 0, stream>>>(out, CH, wq, HD, (long)CH * HD,
                                                 ws0, CH, (long)HD, nullptr, nullptr, 0, CH);
  gemm_kernel<0, 0, 0><<<gqkv, blk, 0, stream>>>(out, CH, wk, HD, (long)CH * HD,
                                                 ws1, CH, (long)HD, nullptr, nullptr, 0, CH);
  gemm_kernel<0, 0, 0><<<gqkv, blk, 0, stream>>>(out, CH, wv, HD, (long)CH * HD,
                                                 ws2, CH, (long)HD, nullptr, nullptr, 0, CH);

  // 3. o = causal_softmax(q k^T / sqrt(D)) v -> out  (B,T,H,D)==(B,T,C)
  const dim3 gattn(SEQ, BATCH * NH);
  attn_kernel<<<gattn, blk, 0, stream>>>(ws0, ws1, ws2, out);

  // 4. x1 = x + o @ wo + bo -> ws0 (Q dead)
  const dim3 gproj(CH / GT, NROWS / GT, 1);
  gemm_kernel<0, 1, 1><<<gproj, blk, 0, stream>>>(out, CH, wo, CH, 0,
                                                  ws0, CH, 0, bo, x, CH, CH);

  // 5. BN1 over (B,C) per t, in place on ws0
  bn_stats<<<SEQ, blk, 0, stream>>>(ws0, mean, rstd);
  bn_apply<<<(NROWS * CH) / 256, blk, 0, stream>>>(ws0, ws0, mean, rstd, bn1g, bn1b);

  // 6. h2 = LN2(x1) -> out (o dead)
  ln_kernel<<<NROWS, blk, 0, stream>>>(ws0, ln2g, ln2b, out);

  // 7. FF in 4 row-chunks: ff1 chunk -> ws1 (K dead), then
  //    x2 chunk = X1 chunk + ff1 @ w2 + b2, written IN PLACE over ws0 rows.
  const dim3 gff1(FFDIM / GT, FFCHUNK / GT, 1);
  const dim3 gff2(CH / GT, FFCHUNK / GT, 1);
  for (int c = 0; c < NROWS / FFCHUNK; ++c) {
    const size_t r0 = (size_t)c * FFCHUNK;
    gemm_kernel<1, 1, 0><<<gff1, blk, 0, stream>>>(out + r0 * CH, CH, w1, FFDIM, 0,
                                                   ws1, FFDIM, 0, b1, nullptr, 0, CH);
    gemm_kernel<0, 1, 1><<<gff2, blk, 0, stream>>>(ws1, FFDIM, w2, CH, 0,
                                                   ws0 + r0 * CH, CH, 0, b2,
                                                   ws0 + r0 * CH, CH, FFDIM);
  }

  // 8. BN2 -> out
  bn_stats<<<SEQ, blk, 0, stream>>>(ws0, mean, rstd);
  bn_apply<<<(NROWS * CH) / 256, blk, 0, stream>>>(ws0, out, mean, rstd, bn2g, bn2b);
}

// Round 3
// 7271.677 us; speedup vs baseline: 1.8563x; 1.8563x over previous
//
#include <hip/hip_runtime.h>
#include <hip/hip_bf16.h>

// Problem constants
constexpr int BATCH = 8;
constexpr int SEQ   = 1024;
constexpr int CH    = 1536;
constexpr int NH    = 12;
constexpr int HD    = 128;       // head dim
constexpr int FFDIM = 6144;      // 4*CH
constexpr int NROWS = BATCH * SEQ;   // 8192
constexpr int FFCHUNK = 2048;    // rows per FF chunk (FFCHUNK*FFDIM == NROWS*CH)
constexpr float EPS = 1e-5f;

// ---------------- block reduction helpers (blockDim == 256) ----------------
__device__ __forceinline__ float block_sum(float v, float* red) {
#pragma unroll
  for (int o = 32; o > 0; o >>= 1) v += __shfl_down(v, o, 64);
  const int w = threadIdx.x >> 6;
  if ((threadIdx.x & 63) == 0) red[w] = v;
  __syncthreads();
  const float r = red[0] + red[1] + red[2] + red[3];
  __syncthreads();
  return r;
}

// ---------------- LayerNorm over last dim (CH) ----------------
__global__ __launch_bounds__(256) void ln_kernel(const float* __restrict__ x,
                                                 const float* __restrict__ g,
                                                 const float* __restrict__ b,
                                                 float* __restrict__ out) {
  __shared__ float row[CH];
  __shared__ float red[4];
  const size_t base = (size_t)blockIdx.x * CH;
  float s = 0.f;
  for (int c = threadIdx.x; c < CH; c += 256) {
    const float v = x[base + c];
    row[c] = v;
    s += v;
  }
  const float mean = block_sum(s, red) * (1.0f / CH);
  float s2 = 0.f;
  for (int c = threadIdx.x; c < CH; c += 256) {
    const float d = row[c] - mean;
    s2 += d * d;
  }
  const float var = block_sum(s2, red) * (1.0f / CH);
  const float rstd = rsqrtf(var + EPS);
  for (int c = threadIdx.x; c < CH; c += 256)
    out[base + c] = (row[c] - mean) * rstd * g[c] + b[c];
}

// ---------------- generic tiled fp32 GEMM ----------------
// C[m,n] (+ bias[n]) (relu) (+ res[m,n]) = sum_k A[m,k]*B[k,n]
// grid.z batches B (stride bstride elems) and C (offset cstride elems).
constexpr int GT = 64;   // output tile (M and N)
constexpr int GK = 16;   // K tile
constexpr int GPAD = 68; // padded leading dim for LDS tiles

template <int RELU, int BIAS, int RES>
__global__ __launch_bounds__(256) void gemm_kernel(
    const float* __restrict__ A, int lda,
    const float* __restrict__ Bm, int ldb, long bstride,
    float* __restrict__ Cm, int ldc, long cstride,
    const float* __restrict__ bias,
    const float* __restrict__ res, int ldr,
    int K) {
  __shared__ __align__(16) float As[GK][GPAD];  // [k][m]
  __shared__ __align__(16) float Bs[GK][GPAD];  // [k][n]
  const int z = blockIdx.z;
  const float* Bp = Bm + (size_t)z * bstride;
  float* Cp = Cm + (size_t)z * cstride;
  const int m0 = blockIdx.y * GT;
  const int n0 = blockIdx.x * GT;
  const int tid = threadIdx.x;
  const int tx = tid & 15, ty = tid >> 4;
  const int arow = tid >> 2, akq = (tid & 3) * 4;
  const int brow = tid >> 4, bcol = (tid & 15) * 4;
  const float* Aptr = A + (size_t)(m0 + arow) * lda + akq;
  const float* Bptr = Bp + (size_t)brow * ldb + n0 + bcol;

  float acc[4][4] = {};
  for (int k0 = 0; k0 < K; k0 += GK) {
    const float4 av = *(const float4*)(Aptr + k0);
    const float4 bv = *(const float4*)(Bptr + (size_t)k0 * ldb);
    __syncthreads();
    As[akq + 0][arow] = av.x;
    As[akq + 1][arow] = av.y;
    As[akq + 2][arow] = av.z;
    As[akq + 3][arow] = av.w;
    *(float4*)&Bs[brow][bcol] = bv;
    __syncthreads();
#pragma unroll
    for (int kk = 0; kk < GK; ++kk) {
      const float4 a = *(const float4*)&As[kk][ty * 4];
      const float4 b = *(const float4*)&Bs[kk][tx * 4];
      acc[0][0] += a.x * b.x; acc[0][1] += a.x * b.y; acc[0][2] += a.x * b.z; acc[0][3] += a.x * b.w;
      acc[1][0] += a.y * b.x; acc[1][1] += a.y * b.y; acc[1][2] += a.y * b.z; acc[1][3] += a.y * b.w;
      acc[2][0] += a.z * b.x; acc[2][1] += a.z * b.y; acc[2][2] += a.z * b.z; acc[2][3] += a.z * b.w;
      acc[3][0] += a.w * b.x; acc[3][1] += a.w * b.y; acc[3][2] += a.w * b.z; acc[3][3] += a.w * b.w;
    }
  }
#pragma unroll
  for (int i = 0; i < 4; ++i) {
    const size_t m = (size_t)(m0 + ty * 4 + i);
#pragma unroll
    for (int j = 0; j < 4; ++j) {
      const int n = n0 + tx * 4 + j;
      float v = acc[i][j];
      if (BIAS) v += bias[n];
      if (RELU) v = fmaxf(v, 0.f);
      if (RES) v += res[m * (size_t)ldr + n];
      Cp[m * (size_t)ldc + n] = v;
    }
  }
}

// ---------------- flash attention: 64-query tile per block ----------------
// q,k,v,o layout: (B, T, H, D): elem (b,t,h,d) at ((b*SEQ+t)*CH + h*HD + d)
// Block (qt, b*NH+h): queries [qt*64, qt*64+64). Iterates key tiles of 64,
// online softmax, PV accumulated in registers (each thread: 4 rows x 8 cols).
constexpr int QT = 64;
constexpr int KT = 64;
constexpr int APAD = 68;

__global__ __launch_bounds__(256) void flash_attn(const float* __restrict__ q,
                                                  const float* __restrict__ k,
                                                  const float* __restrict__ v,
                                                  float* __restrict__ o) {
  __shared__ __align__(16) float Qs[HD][APAD];   // [k][r]  34.8 KB
  __shared__ __align__(16) float Ps[KT][APAD];   // [j][r]  17.4 KB
  __shared__ __align__(16) float KVs[16][132];   // K chunk [kk][c] / V chunk [jj][d]  8.4 KB
  const int tid = threadIdx.x;
  const int tx = tid & 15, ty = tid >> 4;
  const int qt = blockIdx.x;
  const int b = blockIdx.y / NH;
  const int h = blockIdx.y % NH;
  const size_t base = (size_t)b * SEQ * CH + (size_t)h * HD;
  const int q0 = qt * QT;
  const float scale = 0.08838834764831845f;  // 1/sqrt(128)

  // stage Q tile: Qs[k][r] (transposed)
  {
    const int r = tid >> 2, kq = (tid & 3) * 4;
    const float* qp = q + base + (size_t)(q0 + r) * CH;
#pragma unroll
    for (int kb = 0; kb < 8; ++kb) {
      const int kk = kb * 16 + kq;
      const float4 qv = *(const float4*)(qp + kk);
      Qs[kk + 0][r] = qv.x;
      Qs[kk + 1][r] = qv.y;
      Qs[kk + 2][r] = qv.z;
      Qs[kk + 3][r] = qv.w;
    }
  }

  float m_i[4], l_i[4], acc_o[4][8];
#pragma unroll
  for (int i = 0; i < 4; ++i) {
    m_i[i] = -3.0e38f;
    l_i[i] = 0.f;
#pragma unroll
    for (int j = 0; j < 8; ++j) acc_o[i][j] = 0.f;
  }

  const int kload_c = tid >> 2, kload_k = (tid & 3) * 4;

  for (int jt = 0; jt <= qt; ++jt) {
    const int j0 = jt * KT;
    // ---- S = Q K^T (64x64), K staged in 16-wide k-chunks ----
    float s[4][4] = {};
    const float* kp = k + base + (size_t)(j0 + kload_c) * CH + kload_k;
    for (int k0 = 0; k0 < HD; k0 += 16) {
      __syncthreads();
      const float4 kv = *(const float4*)(kp + k0);
      KVs[kload_k + 0][kload_c] = kv.x;
      KVs[kload_k + 1][kload_c] = kv.y;
      KVs[kload_k + 2][kload_c] = kv.z;
      KVs[kload_k + 3][kload_c] = kv.w;
      __syncthreads();
#pragma unroll
      for (int kk = 0; kk < 16; ++kk) {
        const float4 a = *(const float4*)&Qs[k0 + kk][ty * 4];
        const float4 bb = *(const float4*)&KVs[kk][tx * 4];
        s[0][0] += a.x * bb.x; s[0][1] += a.x * bb.y; s[0][2] += a.x * bb.z; s[0][3] += a.x * bb.w;
        s[1][0] += a.y * bb.x; s[1][1] += a.y * bb.y; s[1][2] += a.y * bb.z; s[1][3] += a.y * bb.w;
        s[2][0] += a.z * bb.x; s[2][1] += a.z * bb.y; s[2][2] += a.z * bb.z; s[2][3] += a.z * bb.w;
        s[3][0] += a.w * bb.x; s[3][1] += a.w * bb.y; s[3][2] += a.w * bb.z; s[3][3] += a.w * bb.w;
      }
    }
    // scale + causal mask (only the diagonal tile needs it)
    const bool diag = (jt == qt);
#pragma unroll
    for (int i = 0; i < 4; ++i)
#pragma unroll
      for (int j = 0; j < 4; ++j) {
        float sv = s[i][j] * scale;
        if (diag && (tx * 4 + j > ty * 4 + i)) sv = -3.0e38f;
        s[i][j] = sv;
      }
    // ---- online softmax (row reductions across the 16 tx lanes) ----
    float alpha[4];
#pragma unroll
    for (int i = 0; i < 4; ++i) {
      float rmax = fmaxf(fmaxf(s[i][0], s[i][1]), fmaxf(s[i][2], s[i][3]));
#pragma unroll
      for (int mm = 8; mm >= 1; mm >>= 1) rmax = fmaxf(rmax, __shfl_xor(rmax, mm, 64));
      const float m_new = fmaxf(m_i[i], rmax);
      alpha[i] = __expf(m_i[i] - m_new);
      m_i[i] = m_new;
      float rsum = 0.f;
#pragma unroll
      for (int j = 0; j < 4; ++j) {
        const float p = __expf(s[i][j] - m_new);
        Ps[tx * 4 + j][ty * 4 + i] = p;
        rsum += p;
      }
#pragma unroll
      for (int mm = 8; mm >= 1; mm >>= 1) rsum += __shfl_xor(rsum, mm, 64);
      l_i[i] = l_i[i] * alpha[i] + rsum;
#pragma unroll
      for (int j = 0; j < 8; ++j) acc_o[i][j] *= alpha[i];
    }
    // ---- O += P V, V staged in 16-row chunks ----
    for (int jc = 0; jc < KT; jc += 16) {
      __syncthreads();
#pragma unroll
      for (int rep = 0; rep < 2; ++rep) {
        const int lin = tid + rep * 256;
        const int jj = lin >> 5, dq = (lin & 31) * 4;
        *(float4*)&KVs[jj][dq] = *(const float4*)(v + base + (size_t)(j0 + jc + jj) * CH + dq);
      }
      __syncthreads();
#pragma unroll
      for (int jj = 0; jj < 16; ++jj) {
        const float4 pa = *(const float4*)&Ps[jc + jj][ty * 4];
        const float4 b0 = *(const float4*)&KVs[jj][tx * 4];
        const float4 b1 = *(const float4*)&KVs[jj][64 + tx * 4];
        acc_o[0][0] += pa.x * b0.x; acc_o[0][1] += pa.x * b0.y; acc_o[0][2] += pa.x * b0.z; acc_o[0][3] += pa.x * b0.w;
        acc_o[0][4] += pa.x * b1.x; acc_o[0][5] += pa.x * b1.y; acc_o[0][6] += pa.x * b1.z; acc_o[0][7] += pa.x * b1.w;
        acc_o[1][0] += pa.y * b0.x; acc_o[1][1] += pa.y * b0.y; acc_o[1][2] += pa.y * b0.z; acc_o[1][3] += pa.y * b0.w;
        acc_o[1][4] += pa.y * b1.x; acc_o[1][5] += pa.y * b1.y; acc_o[1][6] += pa.y * b1.z; acc_o[1][7] += pa.y * b1.w;
        acc_o[2][0] += pa.z * b0.x; acc_o[2][1] += pa.z * b0.y; acc_o[2][2] += pa.z * b0.z; acc_o[2][3] += pa.z * b0.w;
        acc_o[2][4] += pa.z * b1.x; acc_o[2][5] += pa.z * b1.y; acc_o[2][6] += pa.z * b1.z; acc_o[2][7] += pa.z * b1.w;
        acc_o[3][0] += pa.w * b0.x; acc_o[3][1] += pa.w * b0.y; acc_o[3][2] += pa.w * b0.z; acc_o[3][3] += pa.w * b0.w;
        acc_o[3][4] += pa.w * b1.x; acc_o[3][5] += pa.w * b1.y; acc_o[3][6] += pa.w * b1.z; acc_o[3][7] += pa.w * b1.w;
      }
    }
  }
  // ---- epilogue: normalize and write O ----
#pragma unroll
  for (int i = 0; i < 4; ++i) {
    const float inv = 1.0f / l_i[i];
    float* op = o + base + (size_t)(q0 + ty * 4 + i) * CH;
    float4 r0, r1;
    r0.x = acc_o[i][0] * inv; r0.y = acc_o[i][1] * inv; r0.z = acc_o[i][2] * inv; r0.w = acc_o[i][3] * inv;
    r1.x = acc_o[i][4] * inv; r1.y = acc_o[i][5] * inv; r1.z = acc_o[i][6] * inv; r1.w = acc_o[i][7] * inv;
    *(float4*)(op + tx * 4) = r0;
    *(float4*)(op + 64 + tx * 4) = r1;
  }
}

// ---------------- BatchNorm over (B, C) per T channel ----------------
__global__ __launch_bounds__(256) void bn_stats(const float* __restrict__ x,
                                                float* __restrict__ mean,
                                                float* __restrict__ rstd) {
  __shared__ float red[4];
  const int t = blockIdx.x;
  float s = 0.f;
  for (int bb = 0; bb < BATCH; ++bb) {
    const float* p = x + ((size_t)bb * SEQ + t) * CH;
    for (int c = threadIdx.x; c < CH; c += 256) s += p[c];
  }
  const float m = block_sum(s, red) * (1.0f / (BATCH * CH));
  float s2 = 0.f;
  for (int bb = 0; bb < BATCH; ++bb) {
    const float* p = x + ((size_t)bb * SEQ + t) * CH;
    for (int c = threadIdx.x; c < CH; c += 256) {
      const float d = p[c] - m;
      s2 += d * d;
    }
  }
  const float var = block_sum(s2, red) * (1.0f / (BATCH * CH));
  if (threadIdx.x == 0) {
    mean[t] = m;
    rstd[t] = rsqrtf(var + EPS);
  }
}

__global__ __launch_bounds__(256) void bn_apply(const float* __restrict__ x,
                                                float* __restrict__ out,
                                                const float* __restrict__ mean,
                                                const float* __restrict__ rstd,
                                                const float* __restrict__ g,
                                                const float* __restrict__ bb) {
  const size_t i = (size_t)blockIdx.x * 256 + threadIdx.x;
  const int t = (int)((i / CH) % SEQ);
  out[i] = (x[i] - mean[t]) * rstd[t] * g[t] + bb[t];
}

// ---------------- launch ----------------
extern "C" void kernel_launch(void* const* d_in, const int* in_sizes, int n_in,
                              void* d_out, int out_size, void* d_ws, size_t ws_size,
                              hipStream_t stream) {
  const float* x    = (const float*)d_in[0];
  const float* wq   = (const float*)d_in[1];
  const float* wk   = (const float*)d_in[2];
  const float* wv   = (const float*)d_in[3];
  const float* wo   = (const float*)d_in[4];
  const float* bo   = (const float*)d_in[5];
  const float* ln1g = (const float*)d_in[6];
  const float* ln1b = (const float*)d_in[7];
  const float* ln2g = (const float*)d_in[8];
  const float* ln2b = (const float*)d_in[9];
  const float* w1   = (const float*)d_in[10];
  const float* b1   = (const float*)d_in[11];
  const float* w2   = (const float*)d_in[12];
  const float* b2   = (const float*)d_in[13];
  const float* bn1g = (const float*)d_in[14];
  const float* bn1b = (const float*)d_in[15];
  const float* bn2g = (const float*)d_in[16];
  const float* bn2b = (const float*)d_in[17];
  float* out = (float*)d_out;   // also used as scratch (h_ln -> o -> h2 -> final)

  // Workspace (floats): 3*NC + stats. ws0: Q -> X1 -> x2; ws1: K -> ff1 chunk; ws2: V
  float* ws = (float*)d_ws;
  const size_t NC = (size_t)NROWS * CH;
  float* ws0 = ws;
  float* ws1 = ws + NC;
  float* ws2 = ws + 2 * NC;
  float* mean = ws + 3 * NC;
  float* rstd = ws + 3 * NC + SEQ;

  const dim3 blk(256);

  // 1. h_ln = LN1(x) -> out
  ln_kernel<<<NROWS, blk, 0, stream>>>(x, ln1g, ln1b, out);

  // 2. q/k/v = h_ln @ w{q,k,v}[h]  (batched over heads via grid.z)
  const dim3 gqkv(HD / GT, NROWS / GT, NH);
  gemm_kernel<0, 0, 0><<<gqkv, blk, 0, stream>>>(out, CH, wq, HD, (long)CH * HD,
                                                 ws0, CH, (long)HD, nullptr, nullptr, 0, CH);
  gemm_kernel<0, 0, 0><<<gqkv, blk, 0, stream>>>(out, CH, wk, HD, (long)CH * HD,
                                                 ws1, CH, (long)HD, nullptr, nullptr, 0, CH);
  gemm_kernel<0, 0, 0><<<gqkv, blk, 0, stream>>>(out, CH, wv, HD, (long)CH * HD,
                                                 ws2, CH, (long)HD, nullptr, nullptr, 0, CH);

  // 3. o = flash_attn(q,k,v) -> out  (B,T,H,D)==(B,T,C)
  const dim3 gattn(SEQ / QT, BATCH * NH);
  flash_attn<<<gattn, blk, 0, stream>>>(ws0, ws1, ws2, out);

  // 4. x1 = x + o @ wo + bo -> ws0 (Q dead)
  const dim3 gproj(CH / GT, NROWS / GT, 1);
  gemm_kernel<0, 1, 1><<<gproj, blk, 0, stream>>>(out, CH, wo, CH, 0,
                                                  ws0, CH, 0, bo, x, CH, CH);

  // 5. BN1 over (B,C) per t, in place on ws0
  bn_stats<<<SEQ, blk, 0, stream>>>(ws0, mean, rstd);
  bn_apply<<<(NROWS * CH) / 256, blk, 0, stream>>>(ws0, ws0, mean, rstd, bn1g, bn1b);

  // 6. h2 = LN2(x1) -> out (o dead)
  ln_kernel<<<NROWS, blk, 0, stream>>>(ws0, ln2g, ln2b, out);

  // 7. FF in 4 row-chunks: ff1 chunk -> ws1, ff2 in place over ws0 rows.
  const dim3 gff1(FFDIM / GT, FFCHUNK / GT, 1);
  const dim3 gff2(CH / GT, FFCHUNK / GT, 1);
  for (int c = 0; c < NROWS / FFCHUNK; ++c) {
    const size_t r0 = (size_t)c * FFCHUNK;
    gemm_kernel<1, 1, 0><<<gff1, blk, 0, stream>>>(out + r0 * CH, CH, w1, FFDIM, 0,
                                                   ws1, FFDIM, 0, b1, nullptr, 0, CH);
    gemm_kernel<0, 1, 1><<<gff2, blk, 0, stream>>>(ws1, FFDIM, w2, CH, 0,
                                                   ws0 + r0 * CH, CH, 0, b2,
                                                   ws0 + r0 * CH, CH, FFDIM);
  }

  // 8. BN2 -> out
  bn_stats<<<SEQ, blk, 0, stream>>>(ws0, mean, rstd);
  bn_apply<<<(NROWS * CH) / 256, blk, 0, stream>>>(ws0, out, mean, rstd, bn2g, bn2b);
}

// Round 4
// 1920.856 us; speedup vs baseline: 7.0271x; 3.7856x over previous
//
#include <hip/hip_runtime.h>
#include <hip/hip_bf16.h>

// Problem constants
constexpr int BATCH = 8;
constexpr int SEQ   = 1024;
constexpr int CH    = 1536;
constexpr int NH    = 12;
constexpr int HD    = 128;       // head dim
constexpr int FFDIM = 6144;      // 4*CH
constexpr int NROWS = BATCH * SEQ;   // 8192
constexpr int QKVLD = 3 * CH;    // 4608, fused QKV row stride
constexpr float EPS = 1e-5f;

typedef unsigned short ushort;
typedef __attribute__((ext_vector_type(8))) ushort us8;
typedef __attribute__((ext_vector_type(4))) ushort us4;
typedef __attribute__((ext_vector_type(8))) __bf16 bf16x8;
typedef __attribute__((ext_vector_type(4))) float f32x4;

__device__ __forceinline__ float b2f(ushort u) {
  return __uint_as_float(((unsigned)u) << 16);
}
__device__ __forceinline__ ushort f2b(float f) {
  __hip_bfloat16 h = __float2bfloat16(f);  // RNE
  return *reinterpret_cast<ushort*>(&h);
}

// ---------------- block reduction helper (blockDim == 256) ----------------
__device__ __forceinline__ float block_sum(float v, float* red) {
#pragma unroll
  for (int o = 32; o > 0; o >>= 1) v += __shfl_down(v, o, 64);
  const int w = threadIdx.x >> 6;
  if ((threadIdx.x & 63) == 0) red[w] = v;
  __syncthreads();
  const float r = red[0] + red[1] + red[2] + red[3];
  __syncthreads();
  return r;
}

// ---------------- LayerNorm over last dim (CH), bf16 output ----------------
__global__ __launch_bounds__(256) void ln_bf16(const float* __restrict__ x,
                                               const float* __restrict__ g,
                                               const float* __restrict__ b,
                                               ushort* __restrict__ out) {
  __shared__ float row[CH];
  __shared__ float red[4];
  const size_t base = (size_t)blockIdx.x * CH;
  float s = 0.f;
  for (int c = threadIdx.x; c < CH; c += 256) {
    const float v = x[base + c];
    row[c] = v;
    s += v;
  }
  const float mean = block_sum(s, red) * (1.0f / CH);
  float s2 = 0.f;
  for (int c = threadIdx.x; c < CH; c += 256) {
    const float d = row[c] - mean;
    s2 += d * d;
  }
  const float var = block_sum(s2, red) * (1.0f / CH);
  const float rstd = rsqrtf(var + EPS);
  for (int c = threadIdx.x; c < CH; c += 256)
    out[base + c] = f2b((row[c] - mean) * rstd * g[c] + b[c]);
}

// ---------------- transpose + fp32->bf16 cast for weights ----------------
// src (R x Cc) fp32 row-major -> dst (Cc x R) bf16 with leading dim ldd.
// grid (Cc/32, R/32, Z); per-z offsets srcZ/dstZ (elements).
__global__ __launch_bounds__(256) void transpose_cast(const float* __restrict__ src,
                                                      ushort* __restrict__ dst,
                                                      int R, int Cc, int ldd,
                                                      long srcZ, long dstZ) {
  __shared__ float tile[32][33];
  src += (size_t)blockIdx.z * srcZ;
  dst += (size_t)blockIdx.z * dstZ;
  const int c0 = blockIdx.x * 32, r0 = blockIdx.y * 32;
  const int tx = threadIdx.x & 31, ty = threadIdx.x >> 5;  // 32 x 8
#pragma unroll
  for (int i = ty; i < 32; i += 8)
    tile[i][tx] = src[(size_t)(r0 + i) * Cc + c0 + tx];
  __syncthreads();
#pragma unroll
  for (int i = ty; i < 32; i += 8)
    dst[(size_t)(c0 + i) * ldd + r0 + tx] = f2b(tile[tx][i]);
}

// ---------------- bf16 MFMA GEMM ----------------
// C[m,n] = sum_k A[m,k] * Bt[n,k]  (+bias[n]) (relu) (+res[m,n])
// A: (M x K) bf16 row-major, lda. Bt: (N x K) bf16 row-major (i.e. B^T), ldb.
// C: fp32 (OUTBF=0) or bf16 (OUTBF=1), ldc. 128x128 tile, BK=32, 4 waves,
// each wave 64x64 via 4x4 grid of 16x16x32 MFMA fragments.
constexpr int BT = 128;   // tile M and N
constexpr int BK = 32;    // K tile (bf16)
constexpr int LDT = 40;   // padded LDS row stride (ushorts): 16B-aligned, low conflict

template <int RELU, int BIAS, int RES, int OUTBF>
__global__ __launch_bounds__(256) void gemm_bf16(
    const ushort* __restrict__ A, int lda,
    const ushort* __restrict__ Bt, int ldb,
    void* __restrict__ Cm, int ldc,
    const float* __restrict__ bias,
    const float* __restrict__ res, int ldr,
    int K) {
  __shared__ ushort As[BT * LDT];  // [m][k], 10 KB
  __shared__ ushort Bs[BT * LDT];  // [n][k], 10 KB
  const int tid = threadIdx.x;
  const int m0 = blockIdx.y * BT;
  const int n0 = blockIdx.x * BT;
  // staging: 512 16B-chunks per tile; thread handles chunks tid and tid+256.
  const int r1 = tid >> 2, kc1 = (tid & 3) * 8;  // chunk tid: row, k-offset (ushorts)
  const int r2 = r1 + 64;                        // chunk tid+256
  const ushort* Ap1 = A + (size_t)(m0 + r1) * lda + kc1;
  const ushort* Ap2 = A + (size_t)(m0 + r2) * lda + kc1;
  const ushort* Bp1 = Bt + (size_t)(n0 + r1) * ldb + kc1;
  const ushort* Bp2 = Bt + (size_t)(n0 + r2) * ldb + kc1;
  // compute mapping
  const int lane = tid & 63;
  const int wv = tid >> 6;
  const int wm = (wv >> 1) * 64, wn = (wv & 1) * 64;
  const int fr = lane & 15;        // fragment row (m or n) within 16
  const int quad = lane >> 4;
  const int koff = quad * 8;

  f32x4 acc[4][4] = {{}};
  for (int k0 = 0; k0 < K; k0 += BK) {
    const us8 a1 = *(const us8*)(Ap1 + k0);
    const us8 a2 = *(const us8*)(Ap2 + k0);
    const us8 b1 = *(const us8*)(Bp1 + k0);
    const us8 b2 = *(const us8*)(Bp2 + k0);
    __syncthreads();
    *(us8*)&As[r1 * LDT + kc1] = a1;
    *(us8*)&As[r2 * LDT + kc1] = a2;
    *(us8*)&Bs[r1 * LDT + kc1] = b1;
    *(us8*)&Bs[r2 * LDT + kc1] = b2;
    __syncthreads();
    bf16x8 af[4], bf[4];
#pragma unroll
    for (int mi = 0; mi < 4; ++mi)
      af[mi] = *(const bf16x8*)&As[(wm + mi * 16 + fr) * LDT + koff];
#pragma unroll
    for (int ni = 0; ni < 4; ++ni)
      bf[ni] = *(const bf16x8*)&Bs[(wn + ni * 16 + fr) * LDT + koff];
#pragma unroll
    for (int mi = 0; mi < 4; ++mi)
#pragma unroll
      for (int ni = 0; ni < 4; ++ni)
        acc[mi][ni] = __builtin_amdgcn_mfma_f32_16x16x32_bf16(af[mi], bf[ni], acc[mi][ni], 0, 0, 0);
  }
  // epilogue: C/D layout col=lane&15, row=quad*4+reg
#pragma unroll
  for (int ni = 0; ni < 4; ++ni) {
    const int col = n0 + wn + ni * 16 + fr;
    const float bs = BIAS ? bias[col] : 0.f;
#pragma unroll
    for (int mi = 0; mi < 4; ++mi) {
      const int rowb = m0 + wm + mi * 16 + quad * 4;
#pragma unroll
      for (int r = 0; r < 4; ++r) {
        float v = acc[mi][ni][r] + bs;
        if (RELU) v = fmaxf(v, 0.f);
        const size_t idx = (size_t)(rowb + r) * ldc + col;
        if (RES) v += res[(size_t)(rowb + r) * ldr + col];
        if (OUTBF) ((ushort*)Cm)[idx] = f2b(v);
        else       ((float*)Cm)[idx] = v;
      }
    }
  }
}

// ---------------- flash attention (bf16 inputs/outputs, fp32 compute) -----
// q,k,v: bf16 with row stride ld (fused QKV buffer); per (b,h) base col h*HD.
// o: bf16 row stride ldo. 64-query tile per block, 64-key tiles, online softmax.
constexpr int QT = 64;
constexpr int KT = 64;
constexpr int APAD = 68;

__global__ __launch_bounds__(256) void flash_attn(const ushort* __restrict__ q,
                                                  const ushort* __restrict__ k,
                                                  const ushort* __restrict__ v,
                                                  ushort* __restrict__ o,
                                                  int ld, int ldo) {
  __shared__ __align__(16) float Qs[HD][APAD];   // [k][r]
  __shared__ __align__(16) float Ps[KT][APAD];   // [j][r]
  __shared__ __align__(16) float KVs[16][132];   // K chunk [kk][c] / V chunk [jj][d]
  const int tid = threadIdx.x;
  const int tx = tid & 15, ty = tid >> 4;
  const int qt = blockIdx.x;
  const int b = blockIdx.y / NH;
  const int h = blockIdx.y % NH;
  const size_t base = (size_t)b * SEQ * ld + (size_t)h * HD;
  const int q0 = qt * QT;
  const float scale = 0.08838834764831845f;  // 1/sqrt(128)

  // stage Q tile transposed: Qs[k][r]
  {
    const int r = tid >> 2, kq = (tid & 3) * 8;
    const ushort* qp = q + base + (size_t)(q0 + r) * ld;
#pragma unroll
    for (int kb = 0; kb < HD; kb += 32) {
      const us8 v8 = *(const us8*)(qp + kb + kq);
#pragma unroll
      for (int ii = 0; ii < 8; ++ii) Qs[kb + kq + ii][r] = b2f(v8[ii]);
    }
  }

  float m_i[4], l_i[4], acc_o[4][8];
#pragma unroll
  for (int i = 0; i < 4; ++i) {
    m_i[i] = -3.0e38f;
    l_i[i] = 0.f;
#pragma unroll
    for (int j = 0; j < 8; ++j) acc_o[i][j] = 0.f;
  }

  const int kc = tid >> 2, kk4 = (tid & 3) * 4;

  for (int jt = 0; jt <= qt; ++jt) {
    const int j0 = jt * KT;
    // ---- S = Q K^T, K staged in 16-wide k-chunks ----
    float s[4][4] = {};
    const ushort* kp = k + base + (size_t)(j0 + kc) * ld + kk4;
    for (int k0 = 0; k0 < HD; k0 += 16) {
      __syncthreads();
      const us4 kv = *(const us4*)(kp + k0);
      KVs[kk4 + 0][kc] = b2f(kv[0]);
      KVs[kk4 + 1][kc] = b2f(kv[1]);
      KVs[kk4 + 2][kc] = b2f(kv[2]);
      KVs[kk4 + 3][kc] = b2f(kv[3]);
      __syncthreads();
#pragma unroll
      for (int kk = 0; kk < 16; ++kk) {
        const float4 a = *(const float4*)&Qs[k0 + kk][ty * 4];
        const float4 bb = *(const float4*)&KVs[kk][tx * 4];
        s[0][0] += a.x * bb.x; s[0][1] += a.x * bb.y; s[0][2] += a.x * bb.z; s[0][3] += a.x * bb.w;
        s[1][0] += a.y * bb.x; s[1][1] += a.y * bb.y; s[1][2] += a.y * bb.z; s[1][3] += a.y * bb.w;
        s[2][0] += a.z * bb.x; s[2][1] += a.z * bb.y; s[2][2] += a.z * bb.z; s[2][3] += a.z * bb.w;
        s[3][0] += a.w * bb.x; s[3][1] += a.w * bb.y; s[3][2] += a.w * bb.z; s[3][3] += a.w * bb.w;
      }
    }
    const bool diag = (jt == qt);
#pragma unroll
    for (int i = 0; i < 4; ++i)
#pragma unroll
      for (int j = 0; j < 4; ++j) {
        float sv = s[i][j] * scale;
        if (diag && (tx * 4 + j > ty * 4 + i)) sv = -3.0e38f;
        s[i][j] = sv;
      }
    // ---- online softmax ----
    float alpha[4];
#pragma unroll
    for (int i = 0; i < 4; ++i) {
      float rmax = fmaxf(fmaxf(s[i][0], s[i][1]), fmaxf(s[i][2], s[i][3]));
#pragma unroll
      for (int mm = 8; mm >= 1; mm >>= 1) rmax = fmaxf(rmax, __shfl_xor(rmax, mm, 64));
      const float m_new = fmaxf(m_i[i], rmax);
      alpha[i] = __expf(m_i[i] - m_new);
      m_i[i] = m_new;
      float rsum = 0.f;
#pragma unroll
      for (int j = 0; j < 4; ++j) {
        const float p = __expf(s[i][j] - m_new);
        Ps[tx * 4 + j][ty * 4 + i] = p;
        rsum += p;
      }
#pragma unroll
      for (int mm = 8; mm >= 1; mm >>= 1) rsum += __shfl_xor(rsum, mm, 64);
      l_i[i] = l_i[i] * alpha[i] + rsum;
#pragma unroll
      for (int j = 0; j < 8; ++j) acc_o[i][j] *= alpha[i];
    }
    // ---- O += P V ----
    for (int jc = 0; jc < KT; jc += 16) {
      __syncthreads();
#pragma unroll
      for (int rep = 0; rep < 2; ++rep) {
        const int lin = tid + rep * 256;
        const int jj = lin >> 5, dq = (lin & 31) * 4;
        const us4 vv = *(const us4*)(v + base + (size_t)(j0 + jc + jj) * ld + dq);
        KVs[jj][dq + 0] = b2f(vv[0]);
        KVs[jj][dq + 1] = b2f(vv[1]);
        KVs[jj][dq + 2] = b2f(vv[2]);
        KVs[jj][dq + 3] = b2f(vv[3]);
      }
      __syncthreads();
#pragma unroll
      for (int jj = 0; jj < 16; ++jj) {
        const float4 pa = *(const float4*)&Ps[jc + jj][ty * 4];
        const float4 b0 = *(const float4*)&KVs[jj][tx * 4];
        const float4 b1 = *(const float4*)&KVs[jj][64 + tx * 4];
        acc_o[0][0] += pa.x * b0.x; acc_o[0][1] += pa.x * b0.y; acc_o[0][2] += pa.x * b0.z; acc_o[0][3] += pa.x * b0.w;
        acc_o[0][4] += pa.x * b1.x; acc_o[0][5] += pa.x * b1.y; acc_o[0][6] += pa.x * b1.z; acc_o[0][7] += pa.x * b1.w;
        acc_o[1][0] += pa.y * b0.x; acc_o[1][1] += pa.y * b0.y; acc_o[1][2] += pa.y * b0.z; acc_o[1][3] += pa.y * b0.w;
        acc_o[1][4] += pa.y * b1.x; acc_o[1][5] += pa.y * b1.y; acc_o[1][6] += pa.y * b1.z; acc_o[1][7] += pa.y * b1.w;
        acc_o[2][0] += pa.z * b0.x; acc_o[2][1] += pa.z * b0.y; acc_o[2][2] += pa.z * b0.z; acc_o[2][3] += pa.z * b0.w;
        acc_o[2][4] += pa.z * b1.x; acc_o[2][5] += pa.z * b1.y; acc_o[2][6] += pa.z * b1.z; acc_o[2][7] += pa.z * b1.w;
        acc_o[3][0] += pa.w * b0.x; acc_o[3][1] += pa.w * b0.y; acc_o[3][2] += pa.w * b0.z; acc_o[3][3] += pa.w * b0.w;
        acc_o[3][4] += pa.w * b1.x; acc_o[3][5] += pa.w * b1.y; acc_o[3][6] += pa.w * b1.z; acc_o[3][7] += pa.w * b1.w;
      }
    }
  }
  // ---- epilogue: normalize, cast to bf16, write O ----
#pragma unroll
  for (int i = 0; i < 4; ++i) {
    const float inv = 1.0f / l_i[i];
    ushort* op = o + ((size_t)b * SEQ + q0 + ty * 4 + i) * ldo + (size_t)h * HD;
#pragma unroll
    for (int j = 0; j < 4; ++j) {
      op[tx * 4 + j] = f2b(acc_o[i][j] * inv);
      op[64 + tx * 4 + j] = f2b(acc_o[i][j + 4] * inv);
    }
  }
}

// ---------------- BatchNorm over (B, C) per T channel (fp32) ----------------
__global__ __launch_bounds__(256) void bn_stats(const float* __restrict__ x,
                                                float* __restrict__ mean,
                                                float* __restrict__ rstd) {
  __shared__ float red[4];
  const int t = blockIdx.x;
  float s = 0.f;
  for (int bb = 0; bb < BATCH; ++bb) {
    const float* p = x + ((size_t)bb * SEQ + t) * CH;
    for (int c = threadIdx.x; c < CH; c += 256) s += p[c];
  }
  const float m = block_sum(s, red) * (1.0f / (BATCH * CH));
  float s2 = 0.f;
  for (int bb = 0; bb < BATCH; ++bb) {
    const float* p = x + ((size_t)bb * SEQ + t) * CH;
    for (int c = threadIdx.x; c < CH; c += 256) {
      const float d = p[c] - m;
      s2 += d * d;
    }
  }
  const float var = block_sum(s2, red) * (1.0f / (BATCH * CH));
  if (threadIdx.x == 0) {
    mean[t] = m;
    rstd[t] = rsqrtf(var + EPS);
  }
}

__global__ __launch_bounds__(256) void bn_apply(const float* __restrict__ x,
                                                float* __restrict__ out,
                                                const float* __restrict__ mean,
                                                const float* __restrict__ rstd,
                                                const float* __restrict__ g,
                                                const float* __restrict__ bb) {
  const size_t i = (size_t)blockIdx.x * 256 + threadIdx.x;
  const int t = (int)((i / CH) % SEQ);
  out[i] = (x[i] - mean[t]) * rstd[t] * g[t] + bb[t];
}

// ---------------- launch ----------------
extern "C" void kernel_launch(void* const* d_in, const int* in_sizes, int n_in,
                              void* d_out, int out_size, void* d_ws, size_t ws_size,
                              hipStream_t stream) {
  const float* x    = (const float*)d_in[0];
  const float* wq   = (const float*)d_in[1];
  const float* wk   = (const float*)d_in[2];
  const float* wv   = (const float*)d_in[3];
  const float* wo   = (const float*)d_in[4];
  const float* bo   = (const float*)d_in[5];
  const float* ln1g = (const float*)d_in[6];
  const float* ln1b = (const float*)d_in[7];
  const float* ln2g = (const float*)d_in[8];
  const float* ln2b = (const float*)d_in[9];
  const float* w1   = (const float*)d_in[10];
  const float* b1   = (const float*)d_in[11];
  const float* w2   = (const float*)d_in[12];
  const float* b2   = (const float*)d_in[13];
  const float* bn1g = (const float*)d_in[14];
  const float* bn1b = (const float*)d_in[15];
  const float* bn2g = (const float*)d_in[16];
  const float* bn2b = (const float*)d_in[17];
  float* out = (float*)d_out;   // X1 fp32 residual stream lives here

  // Workspace (ushort units). Peak ~119.6 MB (< proven 151 MB budget).
  ushort* wsu = (ushort*)d_ws;
  const size_t NCs   = (size_t)NROWS * CH;            // 12.58M elems
  ushort* R0    = wsu;                                // h_ln -> o -> h2 (bf16)
  ushort* QKV   = wsu + NCs;                          // 8192 x 4608 bf16
  ushort* wqkvT = wsu + NCs + (size_t)NROWS * QKVLD;  // 4608 x 1536 bf16
  ushort* woT   = wqkvT + (size_t)QKVLD * CH;         // 1536 x 1536 bf16
  float*  meanp = (float*)(woT + (size_t)CH * CH);
  float*  rstdp = meanp + SEQ;
  // after flash_attn, QKV region is dead -> reuse:
  ushort* w1T   = QKV;                                  // 6144 x 1536
  ushort* w2T   = QKV + (size_t)FFDIM * CH;             // 1536 x 6144
  ushort* FF1   = QKV + 2 * (size_t)FFDIM * CH;         // 4096 x 6144 chunk

  const dim3 blk(256);

  // weight prep needed before QKV / proj
  transpose_cast<<<dim3(HD / 32, CH / 32, NH), blk, 0, stream>>>(
      wq, wqkvT, CH, HD, CH, (long)CH * HD, (long)HD * CH);
  transpose_cast<<<dim3(HD / 32, CH / 32, NH), blk, 0, stream>>>(
      wk, wqkvT + (size_t)CH * CH, CH, HD, CH, (long)CH * HD, (long)HD * CH);
  transpose_cast<<<dim3(HD / 32, CH / 32, NH), blk, 0, stream>>>(
      wv, wqkvT + 2 * (size_t)CH * CH, CH, HD, CH, (long)CH * HD, (long)HD * CH);
  transpose_cast<<<dim3(CH / 32, CH / 32, 1), blk, 0, stream>>>(
      wo, woT, CH, CH, CH, 0, 0);

  // 1. h_ln = LN1(x) -> R0 (bf16)
  ln_bf16<<<NROWS, blk, 0, stream>>>(x, ln1g, ln1b, R0);

  // 2. fused QKV GEMM: (8192 x 4608) = h_ln @ [wq|wk|wv]^T
  gemm_bf16<0, 0, 0, 1><<<dim3(QKVLD / BT, NROWS / BT), blk, 0, stream>>>(
      R0, CH, wqkvT, CH, QKV, QKVLD, nullptr, nullptr, 0, CH);

  // 3. o = flash_attn(q,k,v) -> R0 (bf16, (B,T,H,D) == (B,T,C))
  flash_attn<<<dim3(SEQ / QT, BATCH * NH), blk, 0, stream>>>(
      QKV, QKV + CH, QKV + 2 * CH, R0, QKVLD, CH);

  // FF weight prep (QKV region dead now)
  transpose_cast<<<dim3(FFDIM / 32, CH / 32, 1), blk, 0, stream>>>(
      w1, w1T, CH, FFDIM, CH, 0, 0);
  transpose_cast<<<dim3(CH / 32, FFDIM / 32, 1), blk, 0, stream>>>(
      w2, w2T, FFDIM, CH, FFDIM, 0, 0);

  // 4. x1 = x + o @ wo + bo -> out (fp32)
  gemm_bf16<0, 1, 1, 0><<<dim3(CH / BT, NROWS / BT), blk, 0, stream>>>(
      R0, CH, woT, CH, out, CH, bo, x, CH, CH);

  // 5. BN1 in place on out
  bn_stats<<<SEQ, blk, 0, stream>>>(out, meanp, rstdp);
  bn_apply<<<(NROWS * CH) / 256, blk, 0, stream>>>(out, out, meanp, rstdp, bn1g, bn1b);

  // 6. h2 = LN2(x1) -> R0 (bf16)
  ln_bf16<<<NROWS, blk, 0, stream>>>(out, ln2g, ln2b, R0);

  // 7. FF in 2 row-chunks of 4096: ff1 -> FF1 (bf16), ff2 in-place on out rows
  constexpr int FFC = 4096;
  for (int c = 0; c < NROWS / FFC; ++c) {
    const size_t r0 = (size_t)c * FFC;
    gemm_bf16<1, 1, 0, 1><<<dim3(FFDIM / BT, FFC / BT), blk, 0, stream>>>(
        R0 + r0 * CH, CH, w1T, CH, FF1, FFDIM, b1, nullptr, 0, CH);
    gemm_bf16<0, 1, 1, 0><<<dim3(CH / BT, FFC / BT), blk, 0, stream>>>(
        FF1, FFDIM, w2T, FFDIM, out + r0 * CH, CH, b2, out + r0 * CH, CH, FFDIM);
  }

  // 8. BN2 in place on out
  bn_stats<<<SEQ, blk, 0, stream>>>(out, meanp, rstdp);
  bn_apply<<<(NROWS * CH) / 256, blk, 0, stream>>>(out, out, meanp, rstdp, bn2g, bn2b);
}

// Round 5
// 1407.069 us; speedup vs baseline: 9.5930x; 1.3651x over previous
//
#include <hip/hip_runtime.h>
#include <hip/hip_bf16.h>

// Problem constants
constexpr int BATCH = 8;
constexpr int SEQ   = 1024;
constexpr int CH    = 1536;
constexpr int NH    = 12;
constexpr int HD    = 128;       // head dim
constexpr int FFDIM = 6144;      // 4*CH
constexpr int NROWS = BATCH * SEQ;   // 8192
constexpr int QKVLD = 3 * CH;    // 4608, fused QKV row stride
constexpr float EPS = 1e-5f;

typedef unsigned short ushort;
typedef __attribute__((ext_vector_type(8))) ushort us8;
typedef __attribute__((ext_vector_type(8))) __bf16 bf16x8;
typedef __attribute__((ext_vector_type(4))) float f32x4;

__device__ __forceinline__ float b2f(ushort u) {
  return __uint_as_float(((unsigned)u) << 16);
}
__device__ __forceinline__ ushort f2b(float f) {
  __hip_bfloat16 h = __float2bfloat16(f);  // RNE
  return *reinterpret_cast<ushort*>(&h);
}

// ---------------- block reduction helper (blockDim == 256) ----------------
__device__ __forceinline__ float block_sum(float v, float* red) {
#pragma unroll
  for (int o = 32; o > 0; o >>= 1) v += __shfl_down(v, o, 64);
  const int w = threadIdx.x >> 6;
  if ((threadIdx.x & 63) == 0) red[w] = v;
  __syncthreads();
  const float r = red[0] + red[1] + red[2] + red[3];
  __syncthreads();
  return r;
}

// ---------------- LayerNorm over last dim (CH), bf16 output ----------------
__global__ __launch_bounds__(256) void ln_bf16(const float* __restrict__ x,
                                               const float* __restrict__ g,
                                               const float* __restrict__ b,
                                               ushort* __restrict__ out) {
  __shared__ float row[CH];
  __shared__ float red[4];
  const size_t base = (size_t)blockIdx.x * CH;
  float s = 0.f;
  for (int c = threadIdx.x; c < CH; c += 256) {
    const float v = x[base + c];
    row[c] = v;
    s += v;
  }
  const float mean = block_sum(s, red) * (1.0f / CH);
  float s2 = 0.f;
  for (int c = threadIdx.x; c < CH; c += 256) {
    const float d = row[c] - mean;
    s2 += d * d;
  }
  const float var = block_sum(s2, red) * (1.0f / CH);
  const float rstd = rsqrtf(var + EPS);
  for (int c = threadIdx.x; c < CH; c += 256)
    out[base + c] = f2b((row[c] - mean) * rstd * g[c] + b[c]);
}

// ---------------- transpose + fp32->bf16 cast for weights ----------------
__global__ __launch_bounds__(256) void transpose_cast(const float* __restrict__ src,
                                                      ushort* __restrict__ dst,
                                                      int R, int Cc, int ldd,
                                                      long srcZ, long dstZ) {
  __shared__ float tile[32][33];
  src += (size_t)blockIdx.z * srcZ;
  dst += (size_t)blockIdx.z * dstZ;
  const int c0 = blockIdx.x * 32, r0 = blockIdx.y * 32;
  const int tx = threadIdx.x & 31, ty = threadIdx.x >> 5;  // 32 x 8
#pragma unroll
  for (int i = ty; i < 32; i += 8)
    tile[i][tx] = src[(size_t)(r0 + i) * Cc + c0 + tx];
  __syncthreads();
#pragma unroll
  for (int i = ty; i < 32; i += 8)
    dst[(size_t)(c0 + i) * ldd + r0 + tx] = f2b(tile[tx][i]);
}

// ---------------- bf16 MFMA GEMM ----------------
// C[m,n] = sum_k A[m,k] * Bt[n,k]  (+bias[n]) (relu) (+res[m,n])
constexpr int BT = 128;   // tile M and N
constexpr int BK = 32;    // K tile (bf16)
constexpr int LDT = 40;   // padded LDS row stride (ushorts)

template <int RELU, int BIAS, int RES, int OUTBF>
__global__ __launch_bounds__(256) void gemm_bf16(
    const ushort* __restrict__ A, int lda,
    const ushort* __restrict__ Bt, int ldb,
    void* __restrict__ Cm, int ldc,
    const float* __restrict__ bias,
    const float* __restrict__ res, int ldr,
    int K) {
  __shared__ ushort As[BT * LDT];
  __shared__ ushort Bs[BT * LDT];
  const int tid = threadIdx.x;
  const int m0 = blockIdx.y * BT;
  const int n0 = blockIdx.x * BT;
  const int r1 = tid >> 2, kc1 = (tid & 3) * 8;
  const int r2 = r1 + 64;
  const ushort* Ap1 = A + (size_t)(m0 + r1) * lda + kc1;
  const ushort* Ap2 = A + (size_t)(m0 + r2) * lda + kc1;
  const ushort* Bp1 = Bt + (size_t)(n0 + r1) * ldb + kc1;
  const ushort* Bp2 = Bt + (size_t)(n0 + r2) * ldb + kc1;
  const int lane = tid & 63;
  const int wv = tid >> 6;
  const int wm = (wv >> 1) * 64, wn = (wv & 1) * 64;
  const int fr = lane & 15;
  const int quad = lane >> 4;
  const int koff = quad * 8;

  f32x4 acc[4][4] = {{}};
  for (int k0 = 0; k0 < K; k0 += BK) {
    const us8 a1 = *(const us8*)(Ap1 + k0);
    const us8 a2 = *(const us8*)(Ap2 + k0);
    const us8 b1 = *(const us8*)(Bp1 + k0);
    const us8 b2 = *(const us8*)(Bp2 + k0);
    __syncthreads();
    *(us8*)&As[r1 * LDT + kc1] = a1;
    *(us8*)&As[r2 * LDT + kc1] = a2;
    *(us8*)&Bs[r1 * LDT + kc1] = b1;
    *(us8*)&Bs[r2 * LDT + kc1] = b2;
    __syncthreads();
    bf16x8 af[4], bf[4];
#pragma unroll
    for (int mi = 0; mi < 4; ++mi)
      af[mi] = *(const bf16x8*)&As[(wm + mi * 16 + fr) * LDT + koff];
#pragma unroll
    for (int ni = 0; ni < 4; ++ni)
      bf[ni] = *(const bf16x8*)&Bs[(wn + ni * 16 + fr) * LDT + koff];
#pragma unroll
    for (int mi = 0; mi < 4; ++mi)
#pragma unroll
      for (int ni = 0; ni < 4; ++ni)
        acc[mi][ni] = __builtin_amdgcn_mfma_f32_16x16x32_bf16(af[mi], bf[ni], acc[mi][ni], 0, 0, 0);
  }
#pragma unroll
  for (int ni = 0; ni < 4; ++ni) {
    const int col = n0 + wn + ni * 16 + fr;
    const float bs = BIAS ? bias[col] : 0.f;
#pragma unroll
    for (int mi = 0; mi < 4; ++mi) {
      const int rowb = m0 + wm + mi * 16 + quad * 4;
#pragma unroll
      for (int r = 0; r < 4; ++r) {
        float v = acc[mi][ni][r] + bs;
        if (RELU) v = fmaxf(v, 0.f);
        const size_t idx = (size_t)(rowb + r) * ldc + col;
        if (RES) v += res[(size_t)(rowb + r) * ldr + col];
        if (OUTBF) ((ushort*)Cm)[idx] = f2b(v);
        else       ((float*)Cm)[idx] = v;
      }
    }
  }
}

// ---------------- MFMA flash attention ----------------
// q,k,v bf16 rows of stride ld (fused QKV buffer, per-(b,h) col offset h*HD).
// 64-query block, 4 waves; wave w owns query rows [w*16, w*16+16).
// S = Q K^T via MFMA (Q,K frags direct from global), online softmax in
// C-layout regs, P -> LDS (bf16) -> A-frags, V staged transposed in LDS,
// O accumulated in C-layout regs (8 frags = 128 cols).
constexpr int FQT = 64;   // queries per block
constexpr int VLD = 72;   // LDS row stride (ushorts): 16B-aligned, conflict-uniform

__global__ __launch_bounds__(256) void flash_attn_mfma(
    const ushort* __restrict__ q, const ushort* __restrict__ k,
    const ushort* __restrict__ v, ushort* __restrict__ o,
    int ld, int ldo) {
  __shared__ ushort Vt[HD][VLD];     // V^T tile [d][j]   18.4 KB
  __shared__ ushort Ps[4][16][VLD];  // per-wave P tiles  9.2 KB
  const int tid = threadIdx.x;
  const int lane = tid & 63;
  const int w = tid >> 6;
  const int fr = lane & 15;
  const int quad = lane >> 4;
  const int qt = blockIdx.x;
  const int b = blockIdx.y / NH;
  const int h = blockIdx.y % NH;
  const size_t base = (size_t)b * SEQ * ld + (size_t)h * HD;
  const int q0 = qt * FQT;
  const int qrow = q0 + w * 16;
  const float scale = 0.08838834764831845f;  // 1/sqrt(128)

  // Q A-fragments, resident in registers (A[m=fr][k=quad*8+j])
  bf16x8 aq[4];
  {
    const ushort* qp = q + base + (size_t)(qrow + fr) * ld + quad * 8;
#pragma unroll
    for (int ks = 0; ks < 4; ++ks) aq[ks] = *(const bf16x8*)(qp + ks * 32);
  }

  float m_i[4], l_i[4];
  f32x4 oacc[8];
#pragma unroll
  for (int i = 0; i < 4; ++i) { m_i[i] = -3.0e38f; l_i[i] = 0.f; }
#pragma unroll
  for (int n8 = 0; n8 < 8; ++n8) oacc[n8] = (f32x4){0.f, 0.f, 0.f, 0.f};

  for (int jt = 0; jt <= qt; ++jt) {
    const int j0 = jt * FQT;
    // ---- S = Q K^T (16 MFMA); K B-frags direct from global ----
    f32x4 sacc[4];
#pragma unroll
    for (int ni = 0; ni < 4; ++ni) sacc[ni] = (f32x4){0.f, 0.f, 0.f, 0.f};
#pragma unroll
    for (int ks = 0; ks < 4; ++ks) {
      const ushort* kp = k + base + (size_t)(j0 + fr) * ld + ks * 32 + quad * 8;
#pragma unroll
      for (int ni = 0; ni < 4; ++ni) {
        const bf16x8 kf = *(const bf16x8*)(kp + (size_t)(ni * 16) * ld);
        sacc[ni] = __builtin_amdgcn_mfma_f32_16x16x32_bf16(aq[ks], kf, sacc[ni], 0, 0, 0);
      }
    }
    // ---- scale + causal mask + online softmax (C-layout: row=quad*4+i) ----
    const bool diag = (jt == qt);
    float alpha[4];
#pragma unroll
    for (int i = 0; i < 4; ++i) {
      const int qg = qrow + quad * 4 + i;
      float pv[4];
      float vmax = -3.0e38f;
#pragma unroll
      for (int ni = 0; ni < 4; ++ni) {
        float sv = sacc[ni][i] * scale;
        if (diag && (j0 + ni * 16 + fr > qg)) sv = -3.0e38f;
        pv[ni] = sv;
        vmax = fmaxf(vmax, sv);
      }
#pragma unroll
      for (int mm = 8; mm >= 1; mm >>= 1) vmax = fmaxf(vmax, __shfl_xor(vmax, mm, 64));
      const float m_new = fmaxf(m_i[i], vmax);
      alpha[i] = __expf(m_i[i] - m_new);
      m_i[i] = m_new;
      float rsum = 0.f;
#pragma unroll
      for (int ni = 0; ni < 4; ++ni) {
        const float pe = __expf(pv[ni] - m_new);
        Ps[w][quad * 4 + i][ni * 16 + fr] = f2b(pe);
        rsum += pe;
      }
#pragma unroll
      for (int mm = 8; mm >= 1; mm >>= 1) rsum += __shfl_xor(rsum, mm, 64);
      l_i[i] = l_i[i] * alpha[i] + rsum;
#pragma unroll
      for (int n8 = 0; n8 < 8; ++n8) oacc[n8][i] *= alpha[i];
    }
    // ---- stage V^T (cooperative; conflict-free row-writes) ----
    __syncthreads();  // prior-iteration Vt reads complete
#pragma unroll
    for (int rep = 0; rep < 4; ++rep) {
      const int c = tid + rep * 256;  // 1024 us8-chunks
      const int j = c & 63;
      const int dc = c >> 6;          // 0..15
      const us8 vv = *(const us8*)(v + base + (size_t)(j0 + j) * ld + dc * 8);
#pragma unroll
      for (int ii = 0; ii < 8; ++ii) Vt[dc * 8 + ii][j] = vv[ii];
    }
    __syncthreads();
    // ---- O += P V (16 MFMA); P A-frags and V^T B-frags from LDS ----
#pragma unroll
    for (int js = 0; js < 2; ++js) {
      const bf16x8 pf = *(const bf16x8*)&Ps[w][fr][js * 32 + quad * 8];
#pragma unroll
      for (int n8 = 0; n8 < 8; ++n8) {
        const bf16x8 vf = *(const bf16x8*)&Vt[n8 * 16 + fr][js * 32 + quad * 8];
        oacc[n8] = __builtin_amdgcn_mfma_f32_16x16x32_bf16(pf, vf, oacc[n8], 0, 0, 0);
      }
    }
  }
  // ---- epilogue: normalize, cast, write O ----
#pragma unroll
  for (int i = 0; i < 4; ++i) {
    const float inv = 1.0f / l_i[i];
    ushort* op = o + ((size_t)b * SEQ + qrow + quad * 4 + i) * ldo + (size_t)h * HD;
#pragma unroll
    for (int n8 = 0; n8 < 8; ++n8) op[n8 * 16 + fr] = f2b(oacc[n8][i] * inv);
  }
}

// ---------------- BatchNorm over (B, C) per T channel (fp32) ----------------
__global__ __launch_bounds__(256) void bn_stats(const float* __restrict__ x,
                                                float* __restrict__ mean,
                                                float* __restrict__ rstd) {
  __shared__ float red[4];
  const int t = blockIdx.x;
  float s = 0.f;
  for (int bb = 0; bb < BATCH; ++bb) {
    const float* p = x + ((size_t)bb * SEQ + t) * CH;
    for (int c = threadIdx.x; c < CH; c += 256) s += p[c];
  }
  const float m = block_sum(s, red) * (1.0f / (BATCH * CH));
  float s2 = 0.f;
  for (int bb = 0; bb < BATCH; ++bb) {
    const float* p = x + ((size_t)bb * SEQ + t) * CH;
    for (int c = threadIdx.x; c < CH; c += 256) {
      const float d = p[c] - m;
      s2 += d * d;
    }
  }
  const float var = block_sum(s2, red) * (1.0f / (BATCH * CH));
  if (threadIdx.x == 0) {
    mean[t] = m;
    rstd[t] = rsqrtf(var + EPS);
  }
}

__global__ __launch_bounds__(256) void bn_apply(const float* __restrict__ x,
                                                float* __restrict__ out,
                                                const float* __restrict__ mean,
                                                const float* __restrict__ rstd,
                                                const float* __restrict__ g,
                                                const float* __restrict__ bb) {
  const size_t i = (size_t)blockIdx.x * 256 + threadIdx.x;
  const int t = (int)((i / CH) % SEQ);
  out[i] = (x[i] - mean[t]) * rstd[t] * g[t] + bb[t];
}

// ---------------- launch ----------------
extern "C" void kernel_launch(void* const* d_in, const int* in_sizes, int n_in,
                              void* d_out, int out_size, void* d_ws, size_t ws_size,
                              hipStream_t stream) {
  const float* x    = (const float*)d_in[0];
  const float* wq   = (const float*)d_in[1];
  const float* wk   = (const float*)d_in[2];
  const float* wv   = (const float*)d_in[3];
  const float* wo   = (const float*)d_in[4];
  const float* bo   = (const float*)d_in[5];
  const float* ln1g = (const float*)d_in[6];
  const float* ln1b = (const float*)d_in[7];
  const float* ln2g = (const float*)d_in[8];
  const float* ln2b = (const float*)d_in[9];
  const float* w1   = (const float*)d_in[10];
  const float* b1   = (const float*)d_in[11];
  const float* w2   = (const float*)d_in[12];
  const float* b2   = (const float*)d_in[13];
  const float* bn1g = (const float*)d_in[14];
  const float* bn1b = (const float*)d_in[15];
  const float* bn2g = (const float*)d_in[16];
  const float* bn2b = (const float*)d_in[17];
  float* out = (float*)d_out;   // X1 fp32 residual stream lives here

  // Workspace (ushort units). Peak ~119.6 MB.
  ushort* wsu = (ushort*)d_ws;
  const size_t NCs   = (size_t)NROWS * CH;
  ushort* R0    = wsu;                                // h_ln -> o -> h2 (bf16)
  ushort* QKV   = wsu + NCs;                          // 8192 x 4608 bf16
  ushort* wqkvT = wsu + NCs + (size_t)NROWS * QKVLD;  // 4608 x 1536 bf16
  ushort* woT   = wqkvT + (size_t)QKVLD * CH;         // 1536 x 1536 bf16
  float*  meanp = (float*)(woT + (size_t)CH * CH);
  float*  rstdp = meanp + SEQ;
  ushort* w1T   = QKV;                                // reuse after attention
  ushort* w2T   = QKV + (size_t)FFDIM * CH;
  ushort* FF1   = QKV + 2 * (size_t)FFDIM * CH;

  const dim3 blk(256);

  transpose_cast<<<dim3(HD / 32, CH / 32, NH), blk, 0, stream>>>(
      wq, wqkvT, CH, HD, CH, (long)CH * HD, (long)HD * CH);
  transpose_cast<<<dim3(HD / 32, CH / 32, NH), blk, 0, stream>>>(
      wk, wqkvT + (size_t)CH * CH, CH, HD, CH, (long)CH * HD, (long)HD * CH);
  transpose_cast<<<dim3(HD / 32, CH / 32, NH), blk, 0, stream>>>(
      wv, wqkvT + 2 * (size_t)CH * CH, CH, HD, CH, (long)CH * HD, (long)HD * CH);
  transpose_cast<<<dim3(CH / 32, CH / 32, 1), blk, 0, stream>>>(
      wo, woT, CH, CH, CH, 0, 0);

  // 1. h_ln = LN1(x) -> R0 (bf16)
  ln_bf16<<<NROWS, blk, 0, stream>>>(x, ln1g, ln1b, R0);

  // 2. fused QKV GEMM
  gemm_bf16<0, 0, 0, 1><<<dim3(QKVLD / BT, NROWS / BT), blk, 0, stream>>>(
      R0, CH, wqkvT, CH, QKV, QKVLD, nullptr, nullptr, 0, CH);

  // 3. o = flash_attn(q,k,v) -> R0
  flash_attn_mfma<<<dim3(SEQ / FQT, BATCH * NH), blk, 0, stream>>>(
      QKV, QKV + CH, QKV + 2 * CH, R0, QKVLD, CH);

  // FF weight prep (QKV region dead now)
  transpose_cast<<<dim3(FFDIM / 32, CH / 32, 1), blk, 0, stream>>>(
      w1, w1T, CH, FFDIM, CH, 0, 0);
  transpose_cast<<<dim3(CH / 32, FFDIM / 32, 1), blk, 0, stream>>>(
      w2, w2T, FFDIM, CH, FFDIM, 0, 0);

  // 4. x1 = x + o @ wo + bo -> out (fp32)
  gemm_bf16<0, 1, 1, 0><<<dim3(CH / BT, NROWS / BT), blk, 0, stream>>>(
      R0, CH, woT, CH, out, CH, bo, x, CH, CH);

  // 5. BN1 in place on out
  bn_stats<<<SEQ, blk, 0, stream>>>(out, meanp, rstdp);
  bn_apply<<<(NROWS * CH) / 256, blk, 0, stream>>>(out, out, meanp, rstdp, bn1g, bn1b);

  // 6. h2 = LN2(x1) -> R0 (bf16)
  ln_bf16<<<NROWS, blk, 0, stream>>>(out, ln2g, ln2b, R0);

  // 7. FF in 2 row-chunks of 4096
  constexpr int FFC = 4096;
  for (int c = 0; c < NROWS / FFC; ++c) {
    const size_t r0 = (size_t)c * FFC;
    gemm_bf16<1, 1, 0, 1><<<dim3(FFDIM / BT, FFC / BT), blk, 0, stream>>>(
        R0 + r0 * CH, CH, w1T, CH, FF1, FFDIM, b1, nullptr, 0, CH);
    gemm_bf16<0, 1, 1, 0><<<dim3(CH / BT, FFC / BT), blk, 0, stream>>>(
        FF1, FFDIM, w2T, FFDIM, out + r0 * CH, CH, b2, out + r0 * CH, CH, FFDIM);
  }

  // 8. BN2 in place on out
  bn_stats<<<SEQ, blk, 0, stream>>>(out, meanp, rstdp);
  bn_apply<<<(NROWS * CH) / 256, blk, 0, stream>>>(out, out, meanp, rstdp, bn2g, bn2b);
}

// Round 6
// 1377.015 us; speedup vs baseline: 9.8024x; 1.0218x over previous
//
#include <hip/hip_runtime.h>
#include <hip/hip_bf16.h>

// Problem constants
constexpr int BATCH = 8;
constexpr int SEQ   = 1024;
constexpr int CH    = 1536;
constexpr int NH    = 12;
constexpr int HD    = 128;       // head dim
constexpr int FFDIM = 6144;      // 4*CH
constexpr int NROWS = BATCH * SEQ;   // 8192
constexpr int QKVLD = 3 * CH;    // 4608, fused QKV row stride
constexpr float EPS = 1e-5f;

typedef unsigned short ushort;
typedef __attribute__((ext_vector_type(8))) ushort us8;
typedef __attribute__((ext_vector_type(8))) __bf16 bf16x8;
typedef __attribute__((ext_vector_type(4))) float f32x4;

__device__ __forceinline__ float b2f(ushort u) {
  return __uint_as_float(((unsigned)u) << 16);
}
__device__ __forceinline__ ushort f2b(float f) {
  __hip_bfloat16 h = __float2bfloat16(f);  // RNE
  return *reinterpret_cast<ushort*>(&h);
}

// async global->LDS, 16 bytes per lane. LDS dest = wave-uniform base + lane*16.
__device__ __forceinline__ void g2l16(const ushort* g, ushort* l) {
  __builtin_amdgcn_global_load_lds(
      (const __attribute__((address_space(1))) void*)g,
      (__attribute__((address_space(3))) void*)l, 16, 0, 0);
}

// ---------------- block reduction helper (blockDim == 256) ----------------
__device__ __forceinline__ float block_sum(float v, float* red) {
#pragma unroll
  for (int o = 32; o > 0; o >>= 1) v += __shfl_down(v, o, 64);
  const int w = threadIdx.x >> 6;
  if ((threadIdx.x & 63) == 0) red[w] = v;
  __syncthreads();
  const float r = red[0] + red[1] + red[2] + red[3];
  __syncthreads();
  return r;
}

// ---------------- LayerNorm over last dim (CH), bf16 output ----------------
__global__ __launch_bounds__(256) void ln_bf16(const float* __restrict__ x,
                                               const float* __restrict__ g,
                                               const float* __restrict__ b,
                                               ushort* __restrict__ out) {
  __shared__ float row[CH];
  __shared__ float red[4];
  const size_t base = (size_t)blockIdx.x * CH;
  float s = 0.f;
  for (int c = threadIdx.x; c < CH; c += 256) {
    const float v = x[base + c];
    row[c] = v;
    s += v;
  }
  const float mean = block_sum(s, red) * (1.0f / CH);
  float s2 = 0.f;
  for (int c = threadIdx.x; c < CH; c += 256) {
    const float d = row[c] - mean;
    s2 += d * d;
  }
  const float var = block_sum(s2, red) * (1.0f / CH);
  const float rstd = rsqrtf(var + EPS);
  for (int c = threadIdx.x; c < CH; c += 256)
    out[base + c] = f2b((row[c] - mean) * rstd * g[c] + b[c]);
}

// ---------------- transpose + fp32->bf16 cast for weights ----------------
__global__ __launch_bounds__(256) void transpose_cast(const float* __restrict__ src,
                                                      ushort* __restrict__ dst,
                                                      int R, int Cc, int ldd,
                                                      long srcZ, long dstZ) {
  __shared__ float tile[32][33];
  src += (size_t)blockIdx.z * srcZ;
  dst += (size_t)blockIdx.z * dstZ;
  const int c0 = blockIdx.x * 32, r0 = blockIdx.y * 32;
  const int tx = threadIdx.x & 31, ty = threadIdx.x >> 5;  // 32 x 8
#pragma unroll
  for (int i = ty; i < 32; i += 8)
    tile[i][tx] = src[(size_t)(r0 + i) * Cc + c0 + tx];
  __syncthreads();
#pragma unroll
  for (int i = ty; i < 32; i += 8)
    dst[(size_t)(c0 + i) * ldd + r0 + tx] = f2b(tile[tx][i]);
}

// ---------------- bf16 MFMA GEMM (m97-style: global_load_lds staging) ------
// C[m,n] = sum_k A[m,k] * Bt[n,k]  (+bias[n]) (relu) (+res[m,n])
// A: (M x K) bf16 row-major, lda. Bt: (N x K) bf16 row-major (B^T), ldb.
// 128x128 tile, BK=32. LDS tiles are UNPADDED [128][32] (global_load_lds
// requires dest = wave-uniform base + lane*16B; wave w stages rows
// [32w,32w+32) via 2 instructions of 16 rows, lane i -> row i/4, chunk i&3).
constexpr int BT = 128;   // tile M and N
constexpr int BK = 32;    // K tile (bf16)

template <int RELU, int BIAS, int RES, int OUTBF>
__global__ __launch_bounds__(256) void gemm_bf16(
    const ushort* __restrict__ A, int lda,
    const ushort* __restrict__ Bt, int ldb,
    void* __restrict__ Cm, int ldc,
    const float* __restrict__ bias,
    const float* __restrict__ res, int ldr,
    int K) {
  __shared__ ushort As[BT * BK];  // 8 KB
  __shared__ ushort Bs[BT * BK];  // 8 KB
  const int tid = threadIdx.x;
  const int lane = tid & 63;
  const int wv = tid >> 6;
  const int m0 = blockIdx.y * BT;
  const int n0 = blockIdx.x * BT;
  // staging addresses: wave wv covers tile rows [wv*32, wv*32+32)
  const int srow = wv * 32 + (lane >> 2);      // rows: srow (inst0), srow+16 (inst1)
  const int schunk = (lane & 3) * 8;           // ushort offset within row
  const ushort* gA0 = A + (size_t)(m0 + srow) * lda + schunk;
  const ushort* gA1 = gA0 + (size_t)16 * lda;
  const ushort* gB0 = Bt + (size_t)(n0 + srow) * ldb + schunk;
  const ushort* gB1 = gB0 + (size_t)16 * ldb;
  ushort* lA0 = As + (wv * 32) * BK;           // wave-uniform LDS bases
  ushort* lA1 = lA0 + 16 * BK;
  ushort* lB0 = Bs + (wv * 32) * BK;
  ushort* lB1 = lB0 + 16 * BK;
  // compute mapping
  const int wm = (wv >> 1) * 64, wn = (wv & 1) * 64;
  const int fr = lane & 15;
  const int quad = lane >> 4;
  const int koff = quad * 8;

  f32x4 acc[4][4] = {{}};
  for (int k0 = 0; k0 < K; k0 += BK) {
    __syncthreads();  // prior iteration's ds_reads complete
    g2l16(gA0 + k0, lA0);
    g2l16(gA1 + k0, lA1);
    g2l16(gB0 + k0, lB0);
    g2l16(gB1 + k0, lB1);
    __syncthreads();  // compiler drains vmcnt before barrier
    bf16x8 af[4], bf[4];
#pragma unroll
    for (int mi = 0; mi < 4; ++mi)
      af[mi] = *(const bf16x8*)&As[(wm + mi * 16 + fr) * BK + koff];
#pragma unroll
    for (int ni = 0; ni < 4; ++ni)
      bf[ni] = *(const bf16x8*)&Bs[(wn + ni * 16 + fr) * BK + koff];
#pragma unroll
    for (int mi = 0; mi < 4; ++mi)
#pragma unroll
      for (int ni = 0; ni < 4; ++ni)
        acc[mi][ni] = __builtin_amdgcn_mfma_f32_16x16x32_bf16(af[mi], bf[ni], acc[mi][ni], 0, 0, 0);
  }
  // epilogue: C/D layout col=lane&15, row=quad*4+reg
#pragma unroll
  for (int ni = 0; ni < 4; ++ni) {
    const int col = n0 + wn + ni * 16 + fr;
    const float bs = BIAS ? bias[col] : 0.f;
#pragma unroll
    for (int mi = 0; mi < 4; ++mi) {
      const int rowb = m0 + wm + mi * 16 + quad * 4;
#pragma unroll
      for (int r = 0; r < 4; ++r) {
        float v = acc[mi][ni][r] + bs;
        if (RELU) v = fmaxf(v, 0.f);
        const size_t idx = (size_t)(rowb + r) * ldc + col;
        if (RES) v += res[(size_t)(rowb + r) * ldr + col];
        if (OUTBF) ((ushort*)Cm)[idx] = f2b(v);
        else       ((float*)Cm)[idx] = v;
      }
    }
  }
}

// ---------------- MFMA flash attention (unchanged from R5) ----------------
constexpr int FQT = 64;   // queries per block
constexpr int VLD = 72;   // LDS row stride (ushorts)

__global__ __launch_bounds__(256) void flash_attn_mfma(
    const ushort* __restrict__ q, const ushort* __restrict__ k,
    const ushort* __restrict__ v, ushort* __restrict__ o,
    int ld, int ldo) {
  __shared__ ushort Vt[HD][VLD];     // V^T tile [d][j]
  __shared__ ushort Ps[4][16][VLD];  // per-wave P tiles
  const int tid = threadIdx.x;
  const int lane = tid & 63;
  const int w = tid >> 6;
  const int fr = lane & 15;
  const int quad = lane >> 4;
  const int qt = blockIdx.x;
  const int b = blockIdx.y / NH;
  const int h = blockIdx.y % NH;
  const size_t base = (size_t)b * SEQ * ld + (size_t)h * HD;
  const int q0 = qt * FQT;
  const int qrow = q0 + w * 16;
  const float scale = 0.08838834764831845f;  // 1/sqrt(128)

  bf16x8 aq[4];
  {
    const ushort* qp = q + base + (size_t)(qrow + fr) * ld + quad * 8;
#pragma unroll
    for (int ks = 0; ks < 4; ++ks) aq[ks] = *(const bf16x8*)(qp + ks * 32);
  }

  float m_i[4], l_i[4];
  f32x4 oacc[8];
#pragma unroll
  for (int i = 0; i < 4; ++i) { m_i[i] = -3.0e38f; l_i[i] = 0.f; }
#pragma unroll
  for (int n8 = 0; n8 < 8; ++n8) oacc[n8] = (f32x4){0.f, 0.f, 0.f, 0.f};

  for (int jt = 0; jt <= qt; ++jt) {
    const int j0 = jt * FQT;
    f32x4 sacc[4];
#pragma unroll
    for (int ni = 0; ni < 4; ++ni) sacc[ni] = (f32x4){0.f, 0.f, 0.f, 0.f};
#pragma unroll
    for (int ks = 0; ks < 4; ++ks) {
      const ushort* kp = k + base + (size_t)(j0 + fr) * ld + ks * 32 + quad * 8;
#pragma unroll
      for (int ni = 0; ni < 4; ++ni) {
        const bf16x8 kf = *(const bf16x8*)(kp + (size_t)(ni * 16) * ld);
        sacc[ni] = __builtin_amdgcn_mfma_f32_16x16x32_bf16(aq[ks], kf, sacc[ni], 0, 0, 0);
      }
    }
    const bool diag = (jt == qt);
    float alpha[4];
#pragma unroll
    for (int i = 0; i < 4; ++i) {
      const int qg = qrow + quad * 4 + i;
      float pv[4];
      float vmax = -3.0e38f;
#pragma unroll
      for (int ni = 0; ni < 4; ++ni) {
        float sv = sacc[ni][i] * scale;
        if (diag && (j0 + ni * 16 + fr > qg)) sv = -3.0e38f;
        pv[ni] = sv;
        vmax = fmaxf(vmax, sv);
      }
#pragma unroll
      for (int mm = 8; mm >= 1; mm >>= 1) vmax = fmaxf(vmax, __shfl_xor(vmax, mm, 64));
      const float m_new = fmaxf(m_i[i], vmax);
      alpha[i] = __expf(m_i[i] - m_new);
      m_i[i] = m_new;
      float rsum = 0.f;
#pragma unroll
      for (int ni = 0; ni < 4; ++ni) {
        const float pe = __expf(pv[ni] - m_new);
        Ps[w][quad * 4 + i][ni * 16 + fr] = f2b(pe);
        rsum += pe;
      }
#pragma unroll
      for (int mm = 8; mm >= 1; mm >>= 1) rsum += __shfl_xor(rsum, mm, 64);
      l_i[i] = l_i[i] * alpha[i] + rsum;
#pragma unroll
      for (int n8 = 0; n8 < 8; ++n8) oacc[n8][i] *= alpha[i];
    }
    __syncthreads();
#pragma unroll
    for (int rep = 0; rep < 4; ++rep) {
      const int c = tid + rep * 256;
      const int j = c & 63;
      const int dc = c >> 6;
      const us8 vv = *(const us8*)(v + base + (size_t)(j0 + j) * ld + dc * 8);
#pragma unroll
      for (int ii = 0; ii < 8; ++ii) Vt[dc * 8 + ii][j] = vv[ii];
    }
    __syncthreads();
#pragma unroll
    for (int js = 0; js < 2; ++js) {
      const bf16x8 pf = *(const bf16x8*)&Ps[w][fr][js * 32 + quad * 8];
#pragma unroll
      for (int n8 = 0; n8 < 8; ++n8) {
        const bf16x8 vf = *(const bf16x8*)&Vt[n8 * 16 + fr][js * 32 + quad * 8];
        oacc[n8] = __builtin_amdgcn_mfma_f32_16x16x32_bf16(pf, vf, oacc[n8], 0, 0, 0);
      }
    }
  }
#pragma unroll
  for (int i = 0; i < 4; ++i) {
    const float inv = 1.0f / l_i[i];
    ushort* op = o + ((size_t)b * SEQ + qrow + quad * 4 + i) * ldo + (size_t)h * HD;
#pragma unroll
    for (int n8 = 0; n8 < 8; ++n8) op[n8 * 16 + fr] = f2b(oacc[n8][i] * inv);
  }
}

// ---------------- BatchNorm over (B, C) per T channel (fp32) ----------------
__global__ __launch_bounds__(256) void bn_stats(const float* __restrict__ x,
                                                float* __restrict__ mean,
                                                float* __restrict__ rstd) {
  __shared__ float red[4];
  const int t = blockIdx.x;
  float s = 0.f;
  for (int bb = 0; bb < BATCH; ++bb) {
    const float* p = x + ((size_t)bb * SEQ + t) * CH;
    for (int c = threadIdx.x; c < CH; c += 256) s += p[c];
  }
  const float m = block_sum(s, red) * (1.0f / (BATCH * CH));
  float s2 = 0.f;
  for (int bb = 0; bb < BATCH; ++bb) {
    const float* p = x + ((size_t)bb * SEQ + t) * CH;
    for (int c = threadIdx.x; c < CH; c += 256) {
      const float d = p[c] - m;
      s2 += d * d;
    }
  }
  const float var = block_sum(s2, red) * (1.0f / (BATCH * CH));
  if (threadIdx.x == 0) {
    mean[t] = m;
    rstd[t] = rsqrtf(var + EPS);
  }
}

__global__ __launch_bounds__(256) void bn_apply(const float* __restrict__ x,
                                                float* __restrict__ out,
                                                const float* __restrict__ mean,
                                                const float* __restrict__ rstd,
                                                const float* __restrict__ g,
                                                const float* __restrict__ bb) {
  const size_t i = (size_t)blockIdx.x * 256 + threadIdx.x;
  const int t = (int)((i / CH) % SEQ);
  out[i] = (x[i] - mean[t]) * rstd[t] * g[t] + bb[t];
}

// ---------------- launch ----------------
extern "C" void kernel_launch(void* const* d_in, const int* in_sizes, int n_in,
                              void* d_out, int out_size, void* d_ws, size_t ws_size,
                              hipStream_t stream) {
  const float* x    = (const float*)d_in[0];
  const float* wq   = (const float*)d_in[1];
  const float* wk   = (const float*)d_in[2];
  const float* wv   = (const float*)d_in[3];
  const float* wo   = (const float*)d_in[4];
  const float* bo   = (const float*)d_in[5];
  const float* ln1g = (const float*)d_in[6];
  const float* ln1b = (const float*)d_in[7];
  const float* ln2g = (const float*)d_in[8];
  const float* ln2b = (const float*)d_in[9];
  const float* w1   = (const float*)d_in[10];
  const float* b1   = (const float*)d_in[11];
  const float* w2   = (const float*)d_in[12];
  const float* b2   = (const float*)d_in[13];
  const float* bn1g = (const float*)d_in[14];
  const float* bn1b = (const float*)d_in[15];
  const float* bn2g = (const float*)d_in[16];
  const float* bn2b = (const float*)d_in[17];
  float* out = (float*)d_out;   // X1 fp32 residual stream lives here

  // Workspace (ushort units). Peak ~119.6 MB.
  ushort* wsu = (ushort*)d_ws;
  const size_t NCs   = (size_t)NROWS * CH;
  ushort* R0    = wsu;                                // h_ln -> o -> h2 (bf16)
  ushort* QKV   = wsu + NCs;                          // 8192 x 4608 bf16
  ushort* wqkvT = wsu + NCs + (size_t)NROWS * QKVLD;  // 4608 x 1536 bf16
  ushort* woT   = wqkvT + (size_t)QKVLD * CH;         // 1536 x 1536 bf16
  float*  meanp = (float*)(woT + (size_t)CH * CH);
  float*  rstdp = meanp + SEQ;
  ushort* w1T   = QKV;                                // reuse after attention
  ushort* w2T   = QKV + (size_t)FFDIM * CH;
  ushort* FF1   = QKV + 2 * (size_t)FFDIM * CH;

  const dim3 blk(256);

  transpose_cast<<<dim3(HD / 32, CH / 32, NH), blk, 0, stream>>>(
      wq, wqkvT, CH, HD, CH, (long)CH * HD, (long)HD * CH);
  transpose_cast<<<dim3(HD / 32, CH / 32, NH), blk, 0, stream>>>(
      wk, wqkvT + (size_t)CH * CH, CH, HD, CH, (long)CH * HD, (long)HD * CH);
  transpose_cast<<<dim3(HD / 32, CH / 32, NH), blk, 0, stream>>>(
      wv, wqkvT + 2 * (size_t)CH * CH, CH, HD, CH, (long)CH * HD, (long)HD * CH);
  transpose_cast<<<dim3(CH / 32, CH / 32, 1), blk, 0, stream>>>(
      wo, woT, CH, CH, CH, 0, 0);

  // 1. h_ln = LN1(x) -> R0 (bf16)
  ln_bf16<<<NROWS, blk, 0, stream>>>(x, ln1g, ln1b, R0);

  // 2. fused QKV GEMM
  gemm_bf16<0, 0, 0, 1><<<dim3(QKVLD / BT, NROWS / BT), blk, 0, stream>>>(
      R0, CH, wqkvT, CH, QKV, QKVLD, nullptr, nullptr, 0, CH);

  // 3. o = flash_attn(q,k,v) -> R0
  flash_attn_mfma<<<dim3(SEQ / FQT, BATCH * NH), blk, 0, stream>>>(
      QKV, QKV + CH, QKV + 2 * CH, R0, QKVLD, CH);

  // FF weight prep (QKV region dead now)
  transpose_cast<<<dim3(FFDIM / 32, CH / 32, 1), blk, 0, stream>>>(
      w1, w1T, CH, FFDIM, CH, 0, 0);
  transpose_cast<<<dim3(CH / 32, FFDIM / 32, 1), blk, 0, stream>>>(
      w2, w2T, FFDIM, CH, FFDIM, 0, 0);

  // 4. x1 = x + o @ wo + bo -> out (fp32)
  gemm_bf16<0, 1, 1, 0><<<dim3(CH / BT, NROWS / BT), blk, 0, stream>>>(
      R0, CH, woT, CH, out, CH, bo, x, CH, CH);

  // 5. BN1 in place on out
  bn_stats<<<SEQ, blk, 0, stream>>>(out, meanp, rstdp);
  bn_apply<<<(NROWS * CH) / 256, blk, 0, stream>>>(out, out, meanp, rstdp, bn1g, bn1b);

  // 6. h2 = LN2(x1) -> R0 (bf16)
  ln_bf16<<<NROWS, blk, 0, stream>>>(out, ln2g, ln2b, R0);

  // 7. FF in 2 row-chunks of 4096
  constexpr int FFC = 4096;
  for (int c = 0; c < NROWS / FFC; ++c) {
    const size_t r0 = (size_t)c * FFC;
    gemm_bf16<1, 1, 0, 1><<<dim3(FFDIM / BT, FFC / BT), blk, 0, stream>>>(
        R0 + r0 * CH, CH, w1T, CH, FF1, FFDIM, b1, nullptr, 0, CH);
    gemm_bf16<0, 1, 1, 0><<<dim3(CH / BT, FFC / BT), blk, 0, stream>>>(
        FF1, FFDIM, w2T, FFDIM, out + r0 * CH, CH, b2, out + r0 * CH, CH, FFDIM);
  }

  // 8. BN2 in place on out
  bn_stats<<<SEQ, blk, 0, stream>>>(out, meanp, rstdp);
  bn_apply<<<(NROWS * CH) / 256, blk, 0, stream>>>(out, out, meanp, rstdp, bn2g, bn2b);
}